// Round 1
// baseline (3921.072 us; speedup 1.0000x reference)
//
#include <hip/hip_runtime.h>
#include <hip/hip_bf16.h>

#define BDIM 256
constexpr int Bc = 4, Hc = 128, Wcn = 128, Cc = 768, WM = 65, NB = 8, BS = 96;
constexpr int NROWS = Bc * WM * Hc;              // 33280 spectral rows (b, wm, h)
constexpr size_t NSPEC = (size_t)NROWS * Cc;     // 25,559,040 elems per r/i plane

__device__ __forceinline__ unsigned short f2bf(float f) {
    unsigned u = __float_as_uint(f);
    u = (u + 0x7fffu + ((u >> 16) & 1u)) >> 16;
    return (unsigned short)u;
}
__device__ __forceinline__ float bf2f(unsigned short s) {
    return __uint_as_float(((unsigned)s) << 16);
}

// ---------------- K1: rfft over W, scale 1/128 (full ortho fwd scale) --------
// grid (B*H = 512, C/64 = 12), block 256
__global__ __launch_bounds__(BDIM) void k1_rfft_w(const float* __restrict__ x,
                                                  unsigned short* __restrict__ Rr,
                                                  unsigned short* __restrict__ Ri) {
    __shared__ float xs[128][64];
    __shared__ float2 cs[128];
    const int tid = threadIdx.x;
    const int b = blockIdx.x >> 7, h = blockIdx.x & 127;
    const int c0 = blockIdx.y * 64;
    if (tid < 128) {
        float a = 6.283185307179586f * (float)tid / 128.0f;
        float s, c; __sincosf(a, &s, &c);
        cs[tid] = make_float2(c, s);
    }
    const float* xp = x + ((size_t)(b * 16384 + h * 128)) * 768 + c0;
    for (int idx = tid; idx < 128 * 64; idx += BDIM) {
        int w = idx >> 6, cl = idx & 63;
        xs[w][cl] = xp[(size_t)w * 768 + cl];
    }
    __syncthreads();
    for (int it = tid; it < WM * 16; it += BDIM) {
        int wm = it >> 4, q = it & 15;
        float4 ar = {0, 0, 0, 0}, ai = {0, 0, 0, 0};
        int k = 0;
        #pragma unroll 4
        for (int w = 0; w < 128; ++w) {
            float4 v = *((const float4*)&xs[w][q * 4]);
            float2 t = cs[k];
            ar.x += v.x * t.x; ai.x -= v.x * t.y;
            ar.y += v.y * t.x; ai.y -= v.y * t.y;
            ar.z += v.z * t.x; ai.z -= v.z * t.y;
            ar.w += v.w * t.x; ai.w -= v.w * t.y;
            k = (k + wm) & 127;
        }
        const float sc = 1.0f / 128.0f;
        size_t addr = ((size_t)((b * WM + wm) * 128 + h)) * 768 + c0 + q * 4;
        ushort4 hr; hr.x = f2bf(ar.x * sc); hr.y = f2bf(ar.y * sc); hr.z = f2bf(ar.z * sc); hr.w = f2bf(ar.w * sc);
        ushort4 hi; hi.x = f2bf(ai.x * sc); hi.y = f2bf(ai.y * sc); hi.z = f2bf(ai.z * sc); hi.w = f2bf(ai.w * sc);
        *((ushort4*)&Rr[addr]) = hr;
        *((ushort4*)&Ri[addr]) = hi;
    }
}

// ---------------- K2: complex DFT over H (INV=0 fwd e^{-i}, INV=1 inv e^{+i}) -
// grid (B*WM = 260, C/48 = 16), block 256, in-place per (b,wm,ctile) slab
template <int INV>
__global__ __launch_bounds__(BDIM) void k2_fft_h(unsigned short* __restrict__ Rr,
                                                 unsigned short* __restrict__ Ri) {
    __shared__ float4 D4[128 * 24];   // (r0,i0,r1,i1) per (h, cl-pair)
    __shared__ float2 cs[128];
    const int tid = threadIdx.x;
    const int b = blockIdx.x / WM, wm = blockIdx.x % WM;
    const int c0 = blockIdx.y * 48;
    if (tid < 128) {
        float a = 6.283185307179586f * (float)tid / 128.0f;
        float s, c; __sincosf(a, &s, &c);
        cs[tid] = make_float2(c, s);
    }
    const size_t rowbase = ((size_t)(b * WM + wm)) * 128 * 768 + c0;
    float2* D2 = (float2*)D4;
    for (int idx = tid; idx < 128 * 48; idx += BDIM) {
        int hh = idx / 48, cl = idx % 48;
        size_t a = rowbase + (size_t)hh * 768 + cl;
        D2[hh * 48 + cl] = make_float2(bf2f(Rr[a]), bf2f(Ri[a]));
    }
    __syncthreads();
    for (int it = tid; it < 128 * 24; it += BDIM) {
        int h2 = it / 24, clp = it % 24;
        float ar0 = 0, ai0 = 0, ar1 = 0, ai1 = 0;
        int k = 0;
        #pragma unroll 4
        for (int hh = 0; hh < 128; ++hh) {
            float4 f = D4[hh * 24 + clp];
            float2 t = cs[k];
            if (INV == 0) {
                ar0 += f.x * t.x + f.y * t.y;  ai0 += f.y * t.x - f.x * t.y;
                ar1 += f.z * t.x + f.w * t.y;  ai1 += f.w * t.x - f.z * t.y;
            } else {
                ar0 += f.x * t.x - f.y * t.y;  ai0 += f.y * t.x + f.x * t.y;
                ar1 += f.z * t.x - f.w * t.y;  ai1 += f.w * t.x + f.z * t.y;
            }
            k = (k + h2) & 127;
        }
        size_t a = rowbase + (size_t)h2 * 768 + clp * 2;
        ushort2 ur; ur.x = f2bf(ar0); ur.y = f2bf(ar1);
        ushort2 ui; ui.x = f2bf(ai0); ui.y = f2bf(ai1);
        *((ushort2*)&Rr[a]) = ur;
        *((ushort2*)&Ri[a]) = ui;
    }
}

// ---------------- K3: per-position complex MLP (relu, softshrink) ------------
// grid (NROWS/16 = 2080, NB = 8), block 256, dynamic LDS ~97.5 KB
__global__ __launch_bounds__(BDIM) void k3_mlp(unsigned short* __restrict__ Rr,
                                               unsigned short* __restrict__ Ri,
                                               const float* __restrict__ w1,
                                               const float* __restrict__ b1,
                                               const float* __restrict__ w2,
                                               const float* __restrict__ b2) {
    extern __shared__ char smem[];
    float2* Xp = (float2*)smem;                 // 16*96
    float2* O1p = Xp + 1536;                    // 16*96
    unsigned* w1p = (unsigned*)(O1p + 1536);    // 9216 packed (bf16 r | bf16 i <<16)
    unsigned* w2p = w1p + 9216;                 // 9216
    float* b1r = (float*)(w2p + 9216);
    float* b1i = b1r + 96; float* b2r = b1i + 96; float* b2i = b2r + 96;

    const int tid = threadIdx.x;
    const int blk = blockIdx.y;
    const int pos0 = blockIdx.x * 16;

    const float* w1rg = w1 + blk * 9216;
    const float* w1ig = w1 + 8 * 9216 + blk * 9216;
    const float* w2rg = w2 + blk * 9216;
    const float* w2ig = w2 + 8 * 9216 + blk * 9216;
    for (int idx = tid; idx < 9216; idx += BDIM) {
        w1p[idx] = (unsigned)f2bf(w1rg[idx]) | ((unsigned)f2bf(w1ig[idx]) << 16);
        w2p[idx] = (unsigned)f2bf(w2rg[idx]) | ((unsigned)f2bf(w2ig[idx]) << 16);
    }
    if (tid < 96) {
        b1r[tid] = b1[blk * 96 + tid]; b1i[tid] = b1[768 + blk * 96 + tid];
        b2r[tid] = b2[blk * 96 + tid]; b2i[tid] = b2[768 + blk * 96 + tid];
    }
    for (int idx = tid; idx < 1536; idx += BDIM) {
        int p = idx / 96, i = idx % 96;
        size_t a = (size_t)(pos0 + p) * 768 + blk * 96 + i;
        Xp[idx] = make_float2(bf2f(Rr[a]), bf2f(Ri[a]));
    }
    __syncthreads();

    const int pos = tid >> 4, og = (tid & 15) * 6;
    // layer 1
    float ar[6], ai[6];
    #pragma unroll
    for (int j = 0; j < 6; ++j) { ar[j] = b1r[og + j]; ai[j] = b1i[og + j]; }
    for (int i = 0; i < 96; ++i) {
        float2 xv = Xp[pos * 96 + i];
        #pragma unroll
        for (int j = 0; j < 6; ++j) {
            unsigned u = w1p[i * 96 + og + j];
            float wr = __uint_as_float(u << 16);
            float wi = __uint_as_float(u & 0xffff0000u);
            ar[j] += xv.x * wr - xv.y * wi;
            ai[j] += xv.y * wr + xv.x * wi;
        }
    }
    #pragma unroll
    for (int j = 0; j < 6; ++j)
        O1p[pos * 96 + og + j] = make_float2(fmaxf(ar[j], 0.f), fmaxf(ai[j], 0.f));
    __syncthreads();
    // layer 2
    float cr[6], ci[6];
    #pragma unroll
    for (int j = 0; j < 6; ++j) { cr[j] = b2r[og + j]; ci[j] = b2i[og + j]; }
    for (int o = 0; o < 96; ++o) {
        float2 ov = O1p[pos * 96 + o];
        #pragma unroll
        for (int j = 0; j < 6; ++j) {
            unsigned u = w2p[o * 96 + og + j];
            float wr = __uint_as_float(u << 16);
            float wi = __uint_as_float(u & 0xffff0000u);
            cr[j] += ov.x * wr - ov.y * wi;
            ci[j] += ov.y * wr + ov.x * wi;
        }
    }
    // softshrink -> stage into Xp (dead after layer 1)
    #pragma unroll
    for (int j = 0; j < 6; ++j) {
        float v = cr[j];
        v = (v > 0.01f) ? v - 0.01f : ((v < -0.01f) ? v + 0.01f : 0.f);
        float vi = ci[j];
        vi = (vi > 0.01f) ? vi - 0.01f : ((vi < -0.01f) ? vi + 0.01f : 0.f);
        Xp[pos * 96 + og + j] = make_float2(v, vi);
    }
    __syncthreads();
    for (int idx = tid; idx < 1536; idx += BDIM) {
        int p = idx / 96, i = idx % 96;
        size_t a = (size_t)(pos0 + p) * 768 + blk * 96 + i;
        float2 f = Xp[idx];
        Rr[a] = f2bf(f.x); Ri[a] = f2bf(f.y);
    }
}

// ---------------- K5: c2r inverse over W (+1/128 scale) + residual -----------
// grid (B*H = 512, C/96 = 8), block 256
__global__ __launch_bounds__(BDIM) void k5_irfft_w(const unsigned short* __restrict__ Rr,
                                                   const unsigned short* __restrict__ Ri,
                                                   const float* __restrict__ x,
                                                   float* __restrict__ out) {
    __shared__ float2 Xs[65 * 96];
    __shared__ float2 cs[128];
    const int tid = threadIdx.x;
    const int b = blockIdx.x >> 7, h = blockIdx.x & 127;
    const int c0 = blockIdx.y * 96;
    if (tid < 128) {
        float a = 6.283185307179586f * (float)tid / 128.0f;
        float s, c; __sincosf(a, &s, &c);
        cs[tid] = make_float2(c, s);
    }
    for (int idx = tid; idx < 65 * 96; idx += BDIM) {
        int wm = idx / 96, i = idx % 96;
        size_t a = ((size_t)((b * WM + wm) * 128 + h)) * 768 + c0 + i;
        Xs[idx] = make_float2(bf2f(Rr[a]), bf2f(Ri[a]));
    }
    __syncthreads();
    const float4* Xs4 = (const float4*)Xs;  // [wm*48 + clp] = 2 complex
    for (int it = tid; it < 128 * 48; it += BDIM) {
        int w = it / 48, clp = it % 48;
        float4 f0 = Xs4[clp];             // wm = 0 (imag ignored: c2r conv.)
        float4 f64 = Xs4[64 * 48 + clp];  // wm = 64 Nyquist (imag ignored)
        float sgn = (w & 1) ? -1.f : 1.f;
        float acc0 = f0.x + sgn * f64.x;
        float acc1 = f0.z + sgn * f64.z;
        int k = w & 127;
        #pragma unroll 4
        for (int wm = 1; wm < 64; ++wm) {
            float4 f = Xs4[wm * 48 + clp];
            float2 t = cs[k];
            acc0 += 2.f * (f.x * t.x - f.y * t.y);
            acc1 += 2.f * (f.z * t.x - f.w * t.y);
            k = (k + w) & 127;
        }
        size_t a = ((size_t)(b * 16384 + h * 128 + w)) * 768 + c0 + clp * 2;
        float2 xb = *((const float2*)&x[a]);
        float2 o = make_float2(acc0 * (1.f / 128.f) + xb.x,
                               acc1 * (1.f / 128.f) + xb.y);
        *((float2*)&out[a]) = o;
    }
}

extern "C" void kernel_launch(void* const* d_in, const int* in_sizes, int n_in,
                              void* d_out, int out_size, void* d_ws, size_t ws_size,
                              hipStream_t stream) {
    const float* x  = (const float*)d_in[0];
    const float* w1 = (const float*)d_in[1];
    const float* b1 = (const float*)d_in[2];
    const float* w2 = (const float*)d_in[3];
    const float* b2 = (const float*)d_in[4];
    float* out = (float*)d_out;

    // workspace: two bf16 planes (real, imag) of the spectral tensor, ~102 MB
    unsigned short* Rr = (unsigned short*)d_ws;
    unsigned short* Ri = Rr + NSPEC;

    k1_rfft_w<<<dim3(512, 12), BDIM, 0, stream>>>(x, Rr, Ri);
    k2_fft_h<0><<<dim3(260, 16), BDIM, 0, stream>>>(Rr, Ri);
    size_t sm = 1536 * 8 * 2 + 9216 * 4 * 2 + 96 * 4 * 4;  // 99,840 B
    k3_mlp<<<dim3(2080, 8), BDIM, sm, stream>>>(Rr, Ri, w1, b1, w2, b2);
    k2_fft_h<1><<<dim3(260, 16), BDIM, 0, stream>>>(Rr, Ri);
    k5_irfft_w<<<dim3(512, 8), BDIM, 0, stream>>>(Rr, Ri, x, out);
}

// Round 2
// 2331.637 us; speedup vs baseline: 1.6817x; 1.6817x over previous
//
#include <hip/hip_runtime.h>
#include <hip/hip_bf16.h>

#define BDIM 256
constexpr int Bc = 4, Hc = 128, Wcn = 128, Cc = 768, WM = 65, NB = 8, BS = 96;
constexpr int NROWS = Bc * WM * Hc;              // 33280 spectral rows (b, wm, h)
constexpr size_t NSPEC = (size_t)NROWS * Cc;     // 25,559,040 elems per r/i plane

typedef __attribute__((ext_vector_type(8))) short bf16x8;
typedef __attribute__((ext_vector_type(4))) float f32x4;
typedef __attribute__((ext_vector_type(4))) unsigned int u32x4;

__device__ __forceinline__ unsigned short f2bf(float f) {
    unsigned u = __float_as_uint(f);
    u = (u + 0x7fffu + ((u >> 16) & 1u)) >> 16;
    return (unsigned short)u;
}
__device__ __forceinline__ float bf2f(unsigned short s) {
    return __uint_as_float(((unsigned)s) << 16);
}

// ---------------- K1: rfft over W, scale 1/128 (full ortho fwd scale) --------
// grid (B*H = 512, C/64 = 12), block 256
__global__ __launch_bounds__(BDIM) void k1_rfft_w(const float* __restrict__ x,
                                                  unsigned short* __restrict__ Rr,
                                                  unsigned short* __restrict__ Ri) {
    __shared__ float xs[128][64];
    __shared__ float2 cs[128];
    const int tid = threadIdx.x;
    const int b = blockIdx.x >> 7, h = blockIdx.x & 127;
    const int c0 = blockIdx.y * 64;
    if (tid < 128) {
        float a = 6.283185307179586f * (float)tid / 128.0f;
        float s, c; __sincosf(a, &s, &c);
        cs[tid] = make_float2(c, s);
    }
    const float* xp = x + ((size_t)(b * 16384 + h * 128)) * 768 + c0;
    for (int idx = tid; idx < 128 * 64; idx += BDIM) {
        int w = idx >> 6, cl = idx & 63;
        xs[w][cl] = xp[(size_t)w * 768 + cl];
    }
    __syncthreads();
    for (int it = tid; it < WM * 16; it += BDIM) {
        int wm = it >> 4, q = it & 15;
        float4 ar = {0, 0, 0, 0}, ai = {0, 0, 0, 0};
        int k = 0;
        #pragma unroll 4
        for (int w = 0; w < 128; ++w) {
            float4 v = *((const float4*)&xs[w][q * 4]);
            float2 t = cs[k];
            ar.x += v.x * t.x; ai.x -= v.x * t.y;
            ar.y += v.y * t.x; ai.y -= v.y * t.y;
            ar.z += v.z * t.x; ai.z -= v.z * t.y;
            ar.w += v.w * t.x; ai.w -= v.w * t.y;
            k = (k + wm) & 127;
        }
        const float sc = 1.0f / 128.0f;
        size_t addr = ((size_t)((b * WM + wm) * 128 + h)) * 768 + c0 + q * 4;
        ushort4 hr; hr.x = f2bf(ar.x * sc); hr.y = f2bf(ar.y * sc); hr.z = f2bf(ar.z * sc); hr.w = f2bf(ar.w * sc);
        ushort4 hi; hi.x = f2bf(ai.x * sc); hi.y = f2bf(ai.y * sc); hi.z = f2bf(ai.z * sc); hi.w = f2bf(ai.w * sc);
        *((ushort4*)&Rr[addr]) = hr;
        *((ushort4*)&Ri[addr]) = hi;
    }
}

// ---------------- K2: complex DFT over H (INV=0 fwd e^{-i}, INV=1 inv e^{+i}) -
// grid (B*WM = 260, C/48 = 16), block 256, in-place per (b,wm,ctile) slab
template <int INV>
__global__ __launch_bounds__(BDIM) void k2_fft_h(unsigned short* __restrict__ Rr,
                                                 unsigned short* __restrict__ Ri) {
    __shared__ float4 D4[128 * 24];   // (r0,i0,r1,i1) per (h, cl-pair)
    __shared__ float2 cs[128];
    const int tid = threadIdx.x;
    const int b = blockIdx.x / WM, wm = blockIdx.x % WM;
    const int c0 = blockIdx.y * 48;
    if (tid < 128) {
        float a = 6.283185307179586f * (float)tid / 128.0f;
        float s, c; __sincosf(a, &s, &c);
        cs[tid] = make_float2(c, s);
    }
    const size_t rowbase = ((size_t)(b * WM + wm)) * 128 * 768 + c0;
    float2* D2 = (float2*)D4;
    for (int idx = tid; idx < 128 * 48; idx += BDIM) {
        int hh = idx / 48, cl = idx % 48;
        size_t a = rowbase + (size_t)hh * 768 + cl;
        D2[hh * 48 + cl] = make_float2(bf2f(Rr[a]), bf2f(Ri[a]));
    }
    __syncthreads();
    for (int it = tid; it < 128 * 24; it += BDIM) {
        int h2 = it / 24, clp = it % 24;
        float ar0 = 0, ai0 = 0, ar1 = 0, ai1 = 0;
        int k = 0;
        #pragma unroll 4
        for (int hh = 0; hh < 128; ++hh) {
            float4 f = D4[hh * 24 + clp];
            float2 t = cs[k];
            if (INV == 0) {
                ar0 += f.x * t.x + f.y * t.y;  ai0 += f.y * t.x - f.x * t.y;
                ar1 += f.z * t.x + f.w * t.y;  ai1 += f.w * t.x - f.z * t.y;
            } else {
                ar0 += f.x * t.x - f.y * t.y;  ai0 += f.y * t.x + f.x * t.y;
                ar1 += f.z * t.x - f.w * t.y;  ai1 += f.w * t.x + f.z * t.y;
            }
            k = (k + h2) & 127;
        }
        size_t a = rowbase + (size_t)h2 * 768 + clp * 2;
        ushort2 ur; ur.x = f2bf(ar0); ur.y = f2bf(ar1);
        ushort2 ui; ui.x = f2bf(ai0); ui.y = f2bf(ai1);
        *((ushort2*)&Rr[a]) = ur;
        *((ushort2*)&Ri[a]) = ui;
    }
}

// ---------------- K3: complex MLP via bf16 MFMA -----------------------------
// Augmented real GEMM per block n: [Or Oi] = [Xr Xi] * [[Wr,Wi],[-Wi,Wr]]
// M = 33280 positions, K = N = 192, 2 layers (ReLU, softshrink).
// grid (130, 8), block 256 (4 waves, each owns a 48-col N-strip).
// LDS: 4x WT[96][104] (19,968 B each) + X[128][200] (51,200 B) = 131,072 B.
// All 36 B-fragments (both layers) live in registers.
constexpr int K3_TILES = 2;
__global__ __launch_bounds__(BDIM, 1) void k3_mlp(unsigned short* __restrict__ Rr,
                                                  unsigned short* __restrict__ Ri,
                                                  const float* __restrict__ w1,
                                                  const float* __restrict__ b1,
                                                  const float* __restrict__ w2,
                                                  const float* __restrict__ b2) {
    extern __shared__ char smem[];
    unsigned short* WT = (unsigned short*)smem;        // [mat][96][104], mat: Wr1,Wi1,Wr2,Wi2
    unsigned short* Xs = WT + 4 * 96 * 104;            // [128][200] augmented (r | i)

    const int tid = threadIdx.x;
    const int lane = tid & 63;
    const int w = tid >> 6;          // wave id 0..3
    const int n0 = w * 48;           // this wave's N-strip base
    const int blk = blockIdx.y;

    // ---- stage transposed weights into LDS (coalesced global, scattered LDS)
    {
        const float* src0 = w1 + (size_t)blk * 9216;
        const float* src1 = w1 + (size_t)(8 + blk) * 9216;
        const float* src2 = w2 + (size_t)blk * 9216;
        const float* src3 = w2 + (size_t)(8 + blk) * 9216;
        for (int idx = tid; idx < 9216; idx += BDIM) {
            int k = idx / 96, n = idx % 96;
            int d = n * 104 + k;
            WT[d]             = f2bf(src0[idx]);
            WT[9984 + d]      = f2bf(src1[idx]);
            WT[2 * 9984 + d]  = f2bf(src2[idx]);
            WT[3 * 9984 + d]  = f2bf(src3[idx]);
        }
    }
    // ---- per-lane biases for this wave's 3 column fragments
    float bias1[3], bias2[3];
    #pragma unroll
    for (int c = 0; c < 3; ++c) {
        int n = n0 + c * 16 + (lane & 15);
        bias1[c] = (n < 96) ? b1[blk * 96 + n] : b1[768 + blk * 96 + (n - 96)];
        bias2[c] = (n < 96) ? b2[blk * 96 + n] : b2[768 + blk * 96 + (n - 96)];
    }
    __syncthreads();

    // ---- build all 36 augmented B-fragments in registers
    // B[k][n] = [[Wr,Wi],[-Wi,Wr]]; frag(c,kit): n = n0+16c+(lane&15),
    // k = 32*kit + 8*(lane>>4) + j.  Quadrant uniform per fragment.
    bf16x8 Bf1[3][6], Bf2[3][6];
    #pragma unroll
    for (int c = 0; c < 3; ++c) {
        const int nq = (n0 + c * 16) < 96;
        const int nl = n0 + c * 16 + (lane & 15) - (nq ? 0 : 96);
        #pragma unroll
        for (int kit = 0; kit < 6; ++kit) {
            const int kq = kit < 3;
            const int kl = kit * 32 + ((lane >> 4) << 3) - (kq ? 0 : 96);
            const int quad = kq ? (nq ? 0 : 1) : (nq ? 1 : 0);   // 0=Wr, 1=Wi
            const bool flip = (!kq) && nq;                       // -Wi quadrant
            {
                bf16x8 v = *(const bf16x8*)(WT + quad * 9984 + nl * 104 + kl);
                if (flip) { u32x4 u = __builtin_bit_cast(u32x4, v); u ^= 0x80008000u; v = __builtin_bit_cast(bf16x8, u); }
                Bf1[c][kit] = v;
            }
            {
                bf16x8 v = *(const bf16x8*)(WT + (2 + quad) * 9984 + nl * 104 + kl);
                if (flip) { u32x4 u = __builtin_bit_cast(u32x4, v); u ^= 0x80008000u; v = __builtin_bit_cast(bf16x8, u); }
                Bf2[c][kit] = v;
            }
        }
    }

    const unsigned short* Xl = Xs + (lane & 15) * 200 + ((lane >> 4) << 3);
    const int rowoff = ((lane >> 4) << 2);   // C/D: row = 16r + rowoff + reg

    for (int t = 0; t < K3_TILES; ++t) {
        const int pos0 = (blockIdx.x * K3_TILES + t) * 128;
        // ---- stage X tile (augmented [row][0:96)=Rr, [96:192)=Ri), pad 200
        for (int idx = tid; idx < 3072; idx += BDIM) {
            int plane = idx / 1536, rem = idx % 1536;
            int row = rem / 12, ch = (rem % 12) * 8;
            const unsigned short* src = plane ? Ri : Rr;
            bf16x8 v = *(const bf16x8*)(src + (size_t)(pos0 + row) * 768 + blk * 96 + ch);
            *(bf16x8*)(Xs + row * 200 + plane * 96 + ch) = v;
        }
        __syncthreads();

        // ---- layer 1: acc = X * W1aug + b1
        f32x4 acc[8][3];
        #pragma unroll
        for (int r = 0; r < 8; ++r)
            #pragma unroll
            for (int c = 0; c < 3; ++c)
                acc[r][c] = (f32x4){bias1[c], bias1[c], bias1[c], bias1[c]};
        #pragma unroll
        for (int kit = 0; kit < 6; ++kit) {
            bf16x8 A[8];
            #pragma unroll
            for (int r = 0; r < 8; ++r)
                A[r] = *(const bf16x8*)(Xl + r * 3200 + kit * 32);
            #pragma unroll
            for (int r = 0; r < 8; ++r)
                #pragma unroll
                for (int c = 0; c < 3; ++c)
                    acc[r][c] = __builtin_amdgcn_mfma_f32_16x16x32_bf16(A[r], Bf1[c][kit], acc[r][c], 0, 0, 0);
        }
        __syncthreads();
        // ---- ReLU, write O1 back into X region (augmented layout)
        #pragma unroll
        for (int r = 0; r < 8; ++r)
            #pragma unroll
            for (int c = 0; c < 3; ++c) {
                int ncol = n0 + c * 16 + (lane & 15);
                #pragma unroll
                for (int reg = 0; reg < 4; ++reg) {
                    int row = r * 16 + rowoff + reg;
                    Xs[row * 200 + ncol] = f2bf(fmaxf(acc[r][c][reg], 0.f));
                }
            }
        __syncthreads();

        // ---- layer 2: acc = O1 * W2aug + b2
        #pragma unroll
        for (int r = 0; r < 8; ++r)
            #pragma unroll
            for (int c = 0; c < 3; ++c)
                acc[r][c] = (f32x4){bias2[c], bias2[c], bias2[c], bias2[c]};
        #pragma unroll
        for (int kit = 0; kit < 6; ++kit) {
            bf16x8 A[8];
            #pragma unroll
            for (int r = 0; r < 8; ++r)
                A[r] = *(const bf16x8*)(Xl + r * 3200 + kit * 32);
            #pragma unroll
            for (int r = 0; r < 8; ++r)
                #pragma unroll
                for (int c = 0; c < 3; ++c)
                    acc[r][c] = __builtin_amdgcn_mfma_f32_16x16x32_bf16(A[r], Bf2[c][kit], acc[r][c], 0, 0, 0);
        }
        // ---- softshrink + scatter to global (32B-contiguous 16-lane runs)
        #pragma unroll
        for (int r = 0; r < 8; ++r)
            #pragma unroll
            for (int c = 0; c < 3; ++c) {
                int ncol = n0 + c * 16 + (lane & 15);
                unsigned short* dst = (ncol < 96) ? Rr : Ri;
                int nch = (ncol < 96) ? ncol : ncol - 96;
                #pragma unroll
                for (int reg = 0; reg < 4; ++reg) {
                    int row = r * 16 + rowoff + reg;
                    float v = acc[r][c][reg];
                    v = (v > 0.01f) ? v - 0.01f : ((v < -0.01f) ? v + 0.01f : 0.f);
                    dst[(size_t)(pos0 + row) * 768 + blk * 96 + nch] = f2bf(v);
                }
            }
        __syncthreads();   // protect X region before next tile's staging
    }
}

// ---------------- K5: c2r inverse over W (+1/128 scale) + residual -----------
// grid (B*H = 512, C/96 = 8), block 256
__global__ __launch_bounds__(BDIM) void k5_irfft_w(const unsigned short* __restrict__ Rr,
                                                   const unsigned short* __restrict__ Ri,
                                                   const float* __restrict__ x,
                                                   float* __restrict__ out) {
    __shared__ float2 Xs[65 * 96];
    __shared__ float2 cs[128];
    const int tid = threadIdx.x;
    const int b = blockIdx.x >> 7, h = blockIdx.x & 127;
    const int c0 = blockIdx.y * 96;
    if (tid < 128) {
        float a = 6.283185307179586f * (float)tid / 128.0f;
        float s, c; __sincosf(a, &s, &c);
        cs[tid] = make_float2(c, s);
    }
    for (int idx = tid; idx < 65 * 96; idx += BDIM) {
        int wm = idx / 96, i = idx % 96;
        size_t a = ((size_t)((b * WM + wm) * 128 + h)) * 768 + c0 + i;
        Xs[idx] = make_float2(bf2f(Rr[a]), bf2f(Ri[a]));
    }
    __syncthreads();
    const float4* Xs4 = (const float4*)Xs;  // [wm*48 + clp] = 2 complex
    for (int it = tid; it < 128 * 48; it += BDIM) {
        int w = it / 48, clp = it % 48;
        float4 f0 = Xs4[clp];             // wm = 0 (imag ignored: c2r conv.)
        float4 f64 = Xs4[64 * 48 + clp];  // wm = 64 Nyquist (imag ignored)
        float sgn = (w & 1) ? -1.f : 1.f;
        float acc0 = f0.x + sgn * f64.x;
        float acc1 = f0.z + sgn * f64.z;
        int k = w & 127;
        #pragma unroll 4
        for (int wm = 1; wm < 64; ++wm) {
            float4 f = Xs4[wm * 48 + clp];
            float2 t = cs[k];
            acc0 += 2.f * (f.x * t.x - f.y * t.y);
            acc1 += 2.f * (f.z * t.x - f.w * t.y);
            k = (k + w) & 127;
        }
        size_t a = ((size_t)(b * 16384 + h * 128 + w)) * 768 + c0 + clp * 2;
        float2 xb = *((const float2*)&x[a]);
        float2 o = make_float2(acc0 * (1.f / 128.f) + xb.x,
                               acc1 * (1.f / 128.f) + xb.y);
        *((float2*)&out[a]) = o;
    }
}

extern "C" void kernel_launch(void* const* d_in, const int* in_sizes, int n_in,
                              void* d_out, int out_size, void* d_ws, size_t ws_size,
                              hipStream_t stream) {
    const float* x  = (const float*)d_in[0];
    const float* w1 = (const float*)d_in[1];
    const float* b1 = (const float*)d_in[2];
    const float* w2 = (const float*)d_in[3];
    const float* b2 = (const float*)d_in[4];
    float* out = (float*)d_out;

    // workspace: two bf16 planes (real, imag) of the spectral tensor, ~102 MB
    unsigned short* Rr = (unsigned short*)d_ws;
    unsigned short* Ri = Rr + NSPEC;

    k1_rfft_w<<<dim3(512, 12), BDIM, 0, stream>>>(x, Rr, Ri);
    k2_fft_h<0><<<dim3(260, 16), BDIM, 0, stream>>>(Rr, Ri);
    k3_mlp<<<dim3(130, 8), BDIM, 131072, stream>>>(Rr, Ri, w1, b1, w2, b2);
    k2_fft_h<1><<<dim3(260, 16), BDIM, 0, stream>>>(Rr, Ri);
    k5_irfft_w<<<dim3(512, 8), BDIM, 0, stream>>>(Rr, Ri, x, out);
}

// Round 4
// 1087.440 us; speedup vs baseline: 3.6058x; 2.1442x over previous
//
#include <hip/hip_runtime.h>
#include <hip/hip_bf16.h>

#define BDIM 256
constexpr int Bc = 4, Hc = 128, Wcn = 128, Cc = 768, WM = 65, NB = 8, BS = 96;
constexpr int NROWS = Bc * WM * Hc;              // 33280 spectral rows (b, wm, h)
constexpr size_t NSPEC = (size_t)NROWS * Cc;     // 25,559,040 elems per r/i plane

typedef __attribute__((ext_vector_type(8))) _Float16 f16x8;
typedef __attribute__((ext_vector_type(4))) float f32x4;
typedef __attribute__((ext_vector_type(4))) unsigned int u32x4;

__device__ __forceinline__ unsigned short f2h(float f) {
    return __builtin_bit_cast(unsigned short, (_Float16)f);
}
__device__ __forceinline__ float h2f(unsigned short s) {
    return (float)__builtin_bit_cast(_Float16, s);
}

// ---------------- K1: rfft over W, scale 1/128 (full ortho fwd scale) --------
// grid (B*H = 512, C/64 = 12), block 256
__global__ __launch_bounds__(BDIM) void k1_rfft_w(const float* __restrict__ x,
                                                  unsigned short* __restrict__ Rr,
                                                  unsigned short* __restrict__ Ri) {
    __shared__ float xs[128][64];
    __shared__ float2 cs[128];
    const int tid = threadIdx.x;
    const int b = blockIdx.x >> 7, h = blockIdx.x & 127;
    const int c0 = blockIdx.y * 64;
    if (tid < 128) {
        float a = 6.283185307179586f * (float)tid / 128.0f;
        float s, c; __sincosf(a, &s, &c);
        cs[tid] = make_float2(c, s);
    }
    const float* xp = x + ((size_t)(b * 16384 + h * 128)) * 768 + c0;
    for (int idx = tid; idx < 128 * 64; idx += BDIM) {
        int w = idx >> 6, cl = idx & 63;
        xs[w][cl] = xp[(size_t)w * 768 + cl];
    }
    __syncthreads();
    for (int it = tid; it < WM * 16; it += BDIM) {
        int wm = it >> 4, q = it & 15;
        float4 ar = {0, 0, 0, 0}, ai = {0, 0, 0, 0};
        int k = 0;
        #pragma unroll 4
        for (int w = 0; w < 128; ++w) {
            float4 v = *((const float4*)&xs[w][q * 4]);
            float2 t = cs[k];
            ar.x += v.x * t.x; ai.x -= v.x * t.y;
            ar.y += v.y * t.x; ai.y -= v.y * t.y;
            ar.z += v.z * t.x; ai.z -= v.z * t.y;
            ar.w += v.w * t.x; ai.w -= v.w * t.y;
            k = (k + wm) & 127;
        }
        const float sc = 1.0f / 128.0f;
        size_t addr = ((size_t)((b * WM + wm) * 128 + h)) * 768 + c0 + q * 4;
        ushort4 hr; hr.x = f2h(ar.x * sc); hr.y = f2h(ar.y * sc); hr.z = f2h(ar.z * sc); hr.w = f2h(ar.w * sc);
        ushort4 hi; hi.x = f2h(ai.x * sc); hi.y = f2h(ai.y * sc); hi.z = f2h(ai.z * sc); hi.w = f2h(ai.w * sc);
        *((ushort4*)&Rr[addr]) = hr;
        *((ushort4*)&Ri[addr]) = hi;
    }
}

// ---------------- K2m: complex DFT over H via f16 MFMA ----------------------
// Y[h2][c] = sum_h F[h2][h] X[h][c];  fwd: Yr=C.Xr+S.Xi, Yi=C.Xi-S.Xr
//                                     inv: Yr=C.Xr-S.Xi, Yi=C.Xi+S.Xr
// grid (260 slabs, 2 c-halves), block 256 (4 waves M-split, 32 rows each).
// LDS: C[128][136], S[128][136], Xt_r[64][136], Xt_i[64][136] = 104,448 B
constexpr int TSTR = 136;
template <int INV>
__global__ __launch_bounds__(BDIM, 1) void k2m(unsigned short* __restrict__ Rr,
                                               unsigned short* __restrict__ Ri) {
    extern __shared__ unsigned short lds[];
    unsigned short* Ct = lds;                  // [128][TSTR]
    unsigned short* St = Ct + 128 * TSTR;
    unsigned short* Xtr = St + 128 * TSTR;     // [64][TSTR]
    unsigned short* Xti = Xtr + 64 * TSTR;

    const int tid = threadIdx.x;
    const int lane = tid & 63;
    const int wv = tid >> 6;
    const size_t rowbase = (size_t)blockIdx.x * 128 * 768;
    const int chalf = blockIdx.y * 384;

    // build twiddle tables (p = h2*h mod 128)
    for (int idx = tid; idx < 16384; idx += BDIM) {
        int h2 = idx >> 7, h = idx & 127;
        float th = (float)((h2 * h) & 127) * 0.04908738521234052f;  // 2pi/128
        float s, c; __sincosf(th, &s, &c);
        Ct[h2 * TSTR + h] = f2h(c);
        St[h2 * TSTR + h] = f2h(s);
    }

    const int hme = tid & 127, cgme = tid >> 7;   // staging: h = lane-major
    // pf[p][j]: 8 channels per pass p (16-byte loads: u32x4 = 8 shorts)
    unsigned short pfs[8][8];
    #pragma unroll
    for (int p = 0; p < 8; ++p) {
        const unsigned short* src = (p >> 2) ? Ri : Rr;
        int c0 = chalf + ((p & 3) * 2 + cgme) * 8;
        *(u32x4*)&pfs[p][0] = *(const u32x4*)(src + rowbase + (size_t)hme * 768 + c0);
    }
    __syncthreads();   // twiddle tables ready

    const int arow0 = wv * 32 + (lane & 15);
    const int koff = (lane >> 4) * 8;

    for (int t = 0; t < 6; ++t) {
        // ---- scatter-transpose staged regs into LDS (h lane-major: conflict-free)
        #pragma unroll
        for (int p = 0; p < 8; ++p) {
            unsigned short* dst = (p >> 2) ? Xti : Xtr;
            int cl = ((p & 3) * 2 + cgme) * 8;
            #pragma unroll
            for (int j = 0; j < 8; ++j)
                dst[(cl + j) * TSTR + hme] = pfs[p][j];
        }
        // ---- issue next tile's global loads (in flight during compute)
        if (t < 5) {
            #pragma unroll
            for (int p = 0; p < 8; ++p) {
                const unsigned short* src = (p >> 2) ? Ri : Rr;
                int c0 = chalf + (t + 1) * 64 + ((p & 3) * 2 + cgme) * 8;
                *(u32x4*)&pfs[p][0] = *(const u32x4*)(src + rowbase + (size_t)hme * 768 + c0);
            }
        }
        __syncthreads();

        // ---- MFMA: acc[rf][cf], rf in {0,1} (row frags), cf in {0..3} (col frags)
        f32x4 accr[2][4], acci[2][4];
        #pragma unroll
        for (int rf = 0; rf < 2; ++rf)
            #pragma unroll
            for (int cf = 0; cf < 4; ++cf) {
                accr[rf][cf] = (f32x4){0, 0, 0, 0};
                acci[rf][cf] = (f32x4){0, 0, 0, 0};
            }
        #pragma unroll
        for (int ks = 0; ks < 4; ++ks) {
            f16x8 Cf[2], Sp[2], Sn[2];
            #pragma unroll
            for (int rf = 0; rf < 2; ++rf) {
                int off = (arow0 + rf * 16) * TSTR + ks * 32 + koff;
                Cf[rf] = *(const f16x8*)(Ct + off);
                f16x8 s = *(const f16x8*)(St + off);
                u32x4 u = __builtin_bit_cast(u32x4, s);
                u ^= 0x80008000u;
                Sp[rf] = s;
                Sn[rf] = __builtin_bit_cast(f16x8, u);
            }
            #pragma unroll
            for (int cf = 0; cf < 4; ++cf) {
                int boff = (cf * 16 + (lane & 15)) * TSTR + ks * 32 + koff;
                f16x8 Br = *(const f16x8*)(Xtr + boff);
                f16x8 Bi = *(const f16x8*)(Xti + boff);
                #pragma unroll
                for (int rf = 0; rf < 2; ++rf) {
                    accr[rf][cf] = __builtin_amdgcn_mfma_f32_16x16x32_f16(Cf[rf], Br, accr[rf][cf], 0, 0, 0);
                    accr[rf][cf] = __builtin_amdgcn_mfma_f32_16x16x32_f16(INV ? Sn[rf] : Sp[rf], Bi, accr[rf][cf], 0, 0, 0);
                    acci[rf][cf] = __builtin_amdgcn_mfma_f32_16x16x32_f16(Cf[rf], Bi, acci[rf][cf], 0, 0, 0);
                    acci[rf][cf] = __builtin_amdgcn_mfma_f32_16x16x32_f16(INV ? Sp[rf] : Sn[rf], Br, acci[rf][cf], 0, 0, 0);
                }
            }
        }
        // ---- store Y tile to global (f16 scalar scatter, 32B runs per 16 lanes)
        const int cbase = chalf + t * 64;
        #pragma unroll
        for (int rf = 0; rf < 2; ++rf)
            #pragma unroll
            for (int cf = 0; cf < 4; ++cf) {
                int c = cbase + cf * 16 + (lane & 15);
                int h2b = wv * 32 + rf * 16 + ((lane >> 4) << 2);
                #pragma unroll
                for (int reg = 0; reg < 4; ++reg) {
                    size_t a = rowbase + (size_t)(h2b + reg) * 768 + c;
                    Rr[a] = f2h(accr[rf][cf][reg]);
                    Ri[a] = f2h(acci[rf][cf][reg]);
                }
            }
        __syncthreads();   // LDS safe to overwrite next iteration
    }
}

// ---------------- K3: complex MLP via f16 MFMA ------------------------------
constexpr int K3_TILES = 2;
__global__ __launch_bounds__(BDIM, 1) void k3_mlp(unsigned short* __restrict__ Rr,
                                                  unsigned short* __restrict__ Ri,
                                                  const float* __restrict__ w1,
                                                  const float* __restrict__ b1,
                                                  const float* __restrict__ w2,
                                                  const float* __restrict__ b2) {
    extern __shared__ char smem[];
    unsigned short* WT = (unsigned short*)smem;        // [mat][96][104]
    unsigned short* Xs = WT + 4 * 96 * 104;            // [128][200] augmented

    const int tid = threadIdx.x;
    const int lane = tid & 63;
    const int w = tid >> 6;
    const int n0 = w * 48;
    const int blk = blockIdx.y;

    {
        const float* src0 = w1 + (size_t)blk * 9216;
        const float* src1 = w1 + (size_t)(8 + blk) * 9216;
        const float* src2 = w2 + (size_t)blk * 9216;
        const float* src3 = w2 + (size_t)(8 + blk) * 9216;
        for (int idx = tid; idx < 9216; idx += BDIM) {
            int k = idx / 96, n = idx % 96;
            int d = n * 104 + k;
            WT[d]             = f2h(src0[idx]);
            WT[9984 + d]      = f2h(src1[idx]);
            WT[2 * 9984 + d]  = f2h(src2[idx]);
            WT[3 * 9984 + d]  = f2h(src3[idx]);
        }
    }
    float bias1[3], bias2[3];
    #pragma unroll
    for (int c = 0; c < 3; ++c) {
        int n = n0 + c * 16 + (lane & 15);
        bias1[c] = (n < 96) ? b1[blk * 96 + n] : b1[768 + blk * 96 + (n - 96)];
        bias2[c] = (n < 96) ? b2[blk * 96 + n] : b2[768 + blk * 96 + (n - 96)];
    }
    __syncthreads();

    f16x8 Bf1[3][6], Bf2[3][6];
    #pragma unroll
    for (int c = 0; c < 3; ++c) {
        const int nq = (n0 + c * 16) < 96;
        const int nl = n0 + c * 16 + (lane & 15) - (nq ? 0 : 96);
        #pragma unroll
        for (int kit = 0; kit < 6; ++kit) {
            const int kq = kit < 3;
            const int kl = kit * 32 + ((lane >> 4) << 3) - (kq ? 0 : 96);
            const int quad = kq ? (nq ? 0 : 1) : (nq ? 1 : 0);
            const bool flip = (!kq) && nq;
            {
                f16x8 v = *(const f16x8*)(WT + quad * 9984 + nl * 104 + kl);
                if (flip) { u32x4 u = __builtin_bit_cast(u32x4, v); u ^= 0x80008000u; v = __builtin_bit_cast(f16x8, u); }
                Bf1[c][kit] = v;
            }
            {
                f16x8 v = *(const f16x8*)(WT + (2 + quad) * 9984 + nl * 104 + kl);
                if (flip) { u32x4 u = __builtin_bit_cast(u32x4, v); u ^= 0x80008000u; v = __builtin_bit_cast(f16x8, u); }
                Bf2[c][kit] = v;
            }
        }
    }

    const unsigned short* Xl = Xs + (lane & 15) * 200 + ((lane >> 4) << 3);
    const int rowoff = ((lane >> 4) << 2);

    for (int t = 0; t < K3_TILES; ++t) {
        const int pos0 = (blockIdx.x * K3_TILES + t) * 128;
        // 16-byte moves: 3072 iters x 8 shorts = full 128x192 augmented tile
        for (int idx = tid; idx < 3072; idx += BDIM) {
            int plane = idx / 1536, rem = idx % 1536;
            int row = rem / 12, ch = (rem % 12) * 8;
            const unsigned short* src = plane ? Ri : Rr;
            u32x4 v = *(const u32x4*)(src + (size_t)(pos0 + row) * 768 + blk * 96 + ch);
            *(u32x4*)(Xs + row * 200 + plane * 96 + ch) = v;
        }
        __syncthreads();

        f32x4 acc[8][3];
        #pragma unroll
        for (int r = 0; r < 8; ++r)
            #pragma unroll
            for (int c = 0; c < 3; ++c)
                acc[r][c] = (f32x4){bias1[c], bias1[c], bias1[c], bias1[c]};
        #pragma unroll
        for (int kit = 0; kit < 6; ++kit) {
            f16x8 A[8];
            #pragma unroll
            for (int r = 0; r < 8; ++r)
                A[r] = *(const f16x8*)(Xl + r * 3200 + kit * 32);
            #pragma unroll
            for (int r = 0; r < 8; ++r)
                #pragma unroll
                for (int c = 0; c < 3; ++c)
                    acc[r][c] = __builtin_amdgcn_mfma_f32_16x16x32_f16(A[r], Bf1[c][kit], acc[r][c], 0, 0, 0);
        }
        __syncthreads();
        #pragma unroll
        for (int r = 0; r < 8; ++r)
            #pragma unroll
            for (int c = 0; c < 3; ++c) {
                int ncol = n0 + c * 16 + (lane & 15);
                #pragma unroll
                for (int reg = 0; reg < 4; ++reg) {
                    int row = r * 16 + rowoff + reg;
                    Xs[row * 200 + ncol] = f2h(fmaxf(acc[r][c][reg], 0.f));
                }
            }
        __syncthreads();

        #pragma unroll
        for (int r = 0; r < 8; ++r)
            #pragma unroll
            for (int c = 0; c < 3; ++c)
                acc[r][c] = (f32x4){bias2[c], bias2[c], bias2[c], bias2[c]};
        #pragma unroll
        for (int kit = 0; kit < 6; ++kit) {
            f16x8 A[8];
            #pragma unroll
            for (int r = 0; r < 8; ++r)
                A[r] = *(const f16x8*)(Xl + r * 3200 + kit * 32);
            #pragma unroll
            for (int r = 0; r < 8; ++r)
                #pragma unroll
                for (int c = 0; c < 3; ++c)
                    acc[r][c] = __builtin_amdgcn_mfma_f32_16x16x32_f16(A[r], Bf2[c][kit], acc[r][c], 0, 0, 0);
        }
        #pragma unroll
        for (int r = 0; r < 8; ++r)
            #pragma unroll
            for (int c = 0; c < 3; ++c) {
                int ncol = n0 + c * 16 + (lane & 15);
                unsigned short* dst = (ncol < 96) ? Rr : Ri;
                int nch = (ncol < 96) ? ncol : ncol - 96;
                #pragma unroll
                for (int reg = 0; reg < 4; ++reg) {
                    int row = r * 16 + rowoff + reg;
                    float v = acc[r][c][reg];
                    v = (v > 0.01f) ? v - 0.01f : ((v < -0.01f) ? v + 0.01f : 0.f);
                    dst[(size_t)(pos0 + row) * 768 + blk * 96 + nch] = f2h(v);
                }
            }
        __syncthreads();
    }
}

// ---------------- K5: c2r inverse over W (+1/128 scale) + residual -----------
// grid (B*H = 512, C/96 = 8), block 256
__global__ __launch_bounds__(BDIM) void k5_irfft_w(const unsigned short* __restrict__ Rr,
                                                   const unsigned short* __restrict__ Ri,
                                                   const float* __restrict__ x,
                                                   float* __restrict__ out) {
    __shared__ float2 Xs[65 * 96];
    __shared__ float2 cs[128];
    const int tid = threadIdx.x;
    const int b = blockIdx.x >> 7, h = blockIdx.x & 127;
    const int c0 = blockIdx.y * 96;
    if (tid < 128) {
        float a = 6.283185307179586f * (float)tid / 128.0f;
        float s, c; __sincosf(a, &s, &c);
        cs[tid] = make_float2(c, s);
    }
    for (int idx = tid; idx < 65 * 96; idx += BDIM) {
        int wm = idx / 96, i = idx % 96;
        size_t a = ((size_t)((b * WM + wm) * 128 + h)) * 768 + c0 + i;
        Xs[idx] = make_float2(h2f(Rr[a]), h2f(Ri[a]));
    }
    __syncthreads();
    const float4* Xs4 = (const float4*)Xs;
    for (int it = tid; it < 128 * 48; it += BDIM) {
        int w = it / 48, clp = it % 48;
        float4 f0 = Xs4[clp];
        float4 f64 = Xs4[64 * 48 + clp];
        float sgn = (w & 1) ? -1.f : 1.f;
        float acc0 = f0.x + sgn * f64.x;
        float acc1 = f0.z + sgn * f64.z;
        int k = w & 127;
        #pragma unroll 4
        for (int wm = 1; wm < 64; ++wm) {
            float4 f = Xs4[wm * 48 + clp];
            float2 t = cs[k];
            acc0 += 2.f * (f.x * t.x - f.y * t.y);
            acc1 += 2.f * (f.z * t.x - f.w * t.y);
            k = (k + w) & 127;
        }
        size_t a = ((size_t)(b * 16384 + h * 128 + w)) * 768 + c0 + clp * 2;
        float2 xb = *((const float2*)&x[a]);
        float2 o = make_float2(acc0 * (1.f / 128.f) + xb.x,
                               acc1 * (1.f / 128.f) + xb.y);
        *((float2*)&out[a]) = o;
    }
}

extern "C" void kernel_launch(void* const* d_in, const int* in_sizes, int n_in,
                              void* d_out, int out_size, void* d_ws, size_t ws_size,
                              hipStream_t stream) {
    const float* x  = (const float*)d_in[0];
    const float* w1 = (const float*)d_in[1];
    const float* b1 = (const float*)d_in[2];
    const float* w2 = (const float*)d_in[3];
    const float* b2 = (const float*)d_in[4];
    float* out = (float*)d_out;

    unsigned short* Rr = (unsigned short*)d_ws;
    unsigned short* Ri = Rr + NSPEC;

    const size_t k2lds = (size_t)(2 * 128 * TSTR + 2 * 64 * TSTR) * 2;  // 104,448 B

    k1_rfft_w<<<dim3(512, 12), BDIM, 0, stream>>>(x, Rr, Ri);
    k2m<0><<<dim3(260, 2), BDIM, k2lds, stream>>>(Rr, Ri);
    size_t sm = 1536 * 8 * 2 + 9216 * 4 * 2 + 96 * 4 * 4;  // 99,840 B (k3 uses 131072)
    (void)sm;
    k3_mlp<<<dim3(130, 8), BDIM, 131072, stream>>>(Rr, Ri, w1, b1, w2, b2);
    k2m<1><<<dim3(260, 2), BDIM, k2lds, stream>>>(Rr, Ri);
    k5_irfft_w<<<dim3(512, 8), BDIM, 0, stream>>>(Rr, Ri, x, out);
}

// Round 5
// 666.425 us; speedup vs baseline: 5.8837x; 1.6318x over previous
//
#include <hip/hip_runtime.h>
#include <hip/hip_bf16.h>

#define BDIM 256
constexpr int Bc = 4, Hc = 128, Wcn = 128, Cc = 768, WM = 65, NB = 8, BS = 96;
constexpr int NROWS = Bc * WM * Hc;              // 33280 spectral rows (b, wm, h)
constexpr size_t NSPEC = (size_t)NROWS * Cc;     // 25,559,040 elems per r/i plane

typedef __attribute__((ext_vector_type(8))) _Float16 f16x8;
typedef __attribute__((ext_vector_type(4))) float f32x4;
typedef __attribute__((ext_vector_type(4))) unsigned int u32x4;

__device__ __forceinline__ unsigned short f2h(float f) {
    return __builtin_bit_cast(unsigned short, (_Float16)f);
}
__device__ __forceinline__ float h2f(unsigned short s) {
    return (float)__builtin_bit_cast(_Float16, s);
}

// ---------------- K1: rfft over W, scale 1/128 (full ortho fwd scale) --------
// grid (B*H = 512, C/64 = 12), block 256
__global__ __launch_bounds__(BDIM) void k1_rfft_w(const float* __restrict__ x,
                                                  unsigned short* __restrict__ Rr,
                                                  unsigned short* __restrict__ Ri) {
    __shared__ float xs[128][64];
    __shared__ float2 cs[128];
    const int tid = threadIdx.x;
    const int b = blockIdx.x >> 7, h = blockIdx.x & 127;
    const int c0 = blockIdx.y * 64;
    if (tid < 128) {
        float a = 6.283185307179586f * (float)tid / 128.0f;
        float s, c; __sincosf(a, &s, &c);
        cs[tid] = make_float2(c, s);
    }
    const float* xp = x + ((size_t)(b * 16384 + h * 128)) * 768 + c0;
    for (int idx = tid; idx < 128 * 64; idx += BDIM) {
        int w = idx >> 6, cl = idx & 63;
        xs[w][cl] = xp[(size_t)w * 768 + cl];
    }
    __syncthreads();
    for (int it = tid; it < WM * 16; it += BDIM) {
        int wm = it >> 4, q = it & 15;
        float4 ar = {0, 0, 0, 0}, ai = {0, 0, 0, 0};
        int k = 0;
        #pragma unroll 4
        for (int w = 0; w < 128; ++w) {
            float4 v = *((const float4*)&xs[w][q * 4]);
            float2 t = cs[k];
            ar.x += v.x * t.x; ai.x -= v.x * t.y;
            ar.y += v.y * t.x; ai.y -= v.y * t.y;
            ar.z += v.z * t.x; ai.z -= v.z * t.y;
            ar.w += v.w * t.x; ai.w -= v.w * t.y;
            k = (k + wm) & 127;
        }
        const float sc = 1.0f / 128.0f;
        size_t addr = ((size_t)((b * WM + wm) * 128 + h)) * 768 + c0 + q * 4;
        ushort4 hr; hr.x = f2h(ar.x * sc); hr.y = f2h(ar.y * sc); hr.z = f2h(ar.z * sc); hr.w = f2h(ar.w * sc);
        ushort4 hi; hi.x = f2h(ai.x * sc); hi.y = f2h(ai.y * sc); hi.z = f2h(ai.z * sc); hi.w = f2h(ai.w * sc);
        *((ushort4*)&Rr[addr]) = hr;
        *((ushort4*)&Ri[addr]) = hi;
    }
}

// ---------------- K2m: complex DFT over H via f16 MFMA ----------------------
// Y[h2][c] = sum_h F[h2][h] X[h][c];  fwd: Yr=C.Xr+S.Xi, Yi=C.Xi-S.Xr
//                                     inv: Yr=C.Xr-S.Xi, Yi=C.Xi+S.Xr
// grid (260 slabs, 2 c-halves), block 256 (4 waves M-split, 32 rows each).
// LDS: C[128][136], S[128][136], Xt_r[64][136], Xt_i[64][136] = 104,448 B
constexpr int TSTR = 136;
template <int INV>
__global__ __launch_bounds__(BDIM, 1) void k2m(unsigned short* __restrict__ Rr,
                                               unsigned short* __restrict__ Ri) {
    extern __shared__ unsigned short lds[];
    unsigned short* Ct = lds;                  // [128][TSTR]
    unsigned short* St = Ct + 128 * TSTR;
    unsigned short* Xtr = St + 128 * TSTR;     // [64][TSTR]
    unsigned short* Xti = Xtr + 64 * TSTR;

    const int tid = threadIdx.x;
    const int lane = tid & 63;
    const int wv = tid >> 6;
    const size_t rowbase = (size_t)blockIdx.x * 128 * 768;
    const int chalf = blockIdx.y * 384;

    // build twiddle tables (p = h2*h mod 128)
    for (int idx = tid; idx < 16384; idx += BDIM) {
        int h2 = idx >> 7, h = idx & 127;
        float th = (float)((h2 * h) & 127) * 0.04908738521234052f;  // 2pi/128
        float s, c; __sincosf(th, &s, &c);
        Ct[h2 * TSTR + h] = f2h(c);
        St[h2 * TSTR + h] = f2h(s);
    }

    const int hme = tid & 127, cgme = tid >> 7;   // staging: h = lane-major
    unsigned short pfs[8][8];
    #pragma unroll
    for (int p = 0; p < 8; ++p) {
        const unsigned short* src = (p >> 2) ? Ri : Rr;
        int c0 = chalf + ((p & 3) * 2 + cgme) * 8;
        *(u32x4*)&pfs[p][0] = *(const u32x4*)(src + rowbase + (size_t)hme * 768 + c0);
    }
    __syncthreads();   // twiddle tables ready

    const int arow0 = wv * 32 + (lane & 15);
    const int koff = (lane >> 4) * 8;

    for (int t = 0; t < 6; ++t) {
        // ---- scatter-transpose staged regs into LDS (h lane-major: conflict-free)
        #pragma unroll
        for (int p = 0; p < 8; ++p) {
            unsigned short* dst = (p >> 2) ? Xti : Xtr;
            int cl = ((p & 3) * 2 + cgme) * 8;
            #pragma unroll
            for (int j = 0; j < 8; ++j)
                dst[(cl + j) * TSTR + hme] = pfs[p][j];
        }
        // ---- issue next tile's global loads (in flight during compute)
        if (t < 5) {
            #pragma unroll
            for (int p = 0; p < 8; ++p) {
                const unsigned short* src = (p >> 2) ? Ri : Rr;
                int c0 = chalf + (t + 1) * 64 + ((p & 3) * 2 + cgme) * 8;
                *(u32x4*)&pfs[p][0] = *(const u32x4*)(src + rowbase + (size_t)hme * 768 + c0);
            }
        }
        __syncthreads();

        // ---- MFMA: acc[rf][cf], rf in {0,1} (row frags), cf in {0..3} (col frags)
        f32x4 accr[2][4], acci[2][4];
        #pragma unroll
        for (int rf = 0; rf < 2; ++rf)
            #pragma unroll
            for (int cf = 0; cf < 4; ++cf) {
                accr[rf][cf] = (f32x4){0, 0, 0, 0};
                acci[rf][cf] = (f32x4){0, 0, 0, 0};
            }
        #pragma unroll
        for (int ks = 0; ks < 4; ++ks) {
            f16x8 Cf[2], Sp[2], Sn[2];
            #pragma unroll
            for (int rf = 0; rf < 2; ++rf) {
                int off = (arow0 + rf * 16) * TSTR + ks * 32 + koff;
                Cf[rf] = *(const f16x8*)(Ct + off);
                f16x8 s = *(const f16x8*)(St + off);
                u32x4 u = __builtin_bit_cast(u32x4, s);
                u ^= 0x80008000u;
                Sp[rf] = s;
                Sn[rf] = __builtin_bit_cast(f16x8, u);
            }
            #pragma unroll
            for (int cf = 0; cf < 4; ++cf) {
                int boff = (cf * 16 + (lane & 15)) * TSTR + ks * 32 + koff;
                f16x8 Br = *(const f16x8*)(Xtr + boff);
                f16x8 Bi = *(const f16x8*)(Xti + boff);
                #pragma unroll
                for (int rf = 0; rf < 2; ++rf) {
                    accr[rf][cf] = __builtin_amdgcn_mfma_f32_16x16x32_f16(Cf[rf], Br, accr[rf][cf], 0, 0, 0);
                    accr[rf][cf] = __builtin_amdgcn_mfma_f32_16x16x32_f16(INV ? Sn[rf] : Sp[rf], Bi, accr[rf][cf], 0, 0, 0);
                    acci[rf][cf] = __builtin_amdgcn_mfma_f32_16x16x32_f16(Cf[rf], Bi, acci[rf][cf], 0, 0, 0);
                    acci[rf][cf] = __builtin_amdgcn_mfma_f32_16x16x32_f16(INV ? Sp[rf] : Sn[rf], Br, acci[rf][cf], 0, 0, 0);
                }
            }
        }
        // ---- store Y tile to global (f16 scalar scatter, 32B runs per 16 lanes)
        const int cbase = chalf + t * 64;
        #pragma unroll
        for (int rf = 0; rf < 2; ++rf)
            #pragma unroll
            for (int cf = 0; cf < 4; ++cf) {
                int c = cbase + cf * 16 + (lane & 15);
                int h2b = wv * 32 + rf * 16 + ((lane >> 4) << 2);
                #pragma unroll
                for (int reg = 0; reg < 4; ++reg) {
                    size_t a = rowbase + (size_t)(h2b + reg) * 768 + c;
                    Rr[a] = f2h(accr[rf][cf][reg]);
                    Ri[a] = f2h(acci[rf][cf][reg]);
                }
            }
        __syncthreads();   // LDS safe to overwrite next iteration
    }
}

// ---------------- K3: complex MLP via f16 MFMA ------------------------------
constexpr int K3_TILES = 2;
__global__ __launch_bounds__(BDIM, 1) void k3_mlp(unsigned short* __restrict__ Rr,
                                                  unsigned short* __restrict__ Ri,
                                                  const float* __restrict__ w1,
                                                  const float* __restrict__ b1,
                                                  const float* __restrict__ w2,
                                                  const float* __restrict__ b2) {
    extern __shared__ char smem[];
    unsigned short* WT = (unsigned short*)smem;        // [mat][96][104]
    unsigned short* Xs = WT + 4 * 96 * 104;            // [128][200] augmented

    const int tid = threadIdx.x;
    const int lane = tid & 63;
    const int w = tid >> 6;
    const int n0 = w * 48;
    const int blk = blockIdx.y;

    {
        const float* src0 = w1 + (size_t)blk * 9216;
        const float* src1 = w1 + (size_t)(8 + blk) * 9216;
        const float* src2 = w2 + (size_t)blk * 9216;
        const float* src3 = w2 + (size_t)(8 + blk) * 9216;
        for (int idx = tid; idx < 9216; idx += BDIM) {
            int k = idx / 96, n = idx % 96;
            int d = n * 104 + k;
            WT[d]             = f2h(src0[idx]);
            WT[9984 + d]      = f2h(src1[idx]);
            WT[2 * 9984 + d]  = f2h(src2[idx]);
            WT[3 * 9984 + d]  = f2h(src3[idx]);
        }
    }
    float bias1[3], bias2[3];
    #pragma unroll
    for (int c = 0; c < 3; ++c) {
        int n = n0 + c * 16 + (lane & 15);
        bias1[c] = (n < 96) ? b1[blk * 96 + n] : b1[768 + blk * 96 + (n - 96)];
        bias2[c] = (n < 96) ? b2[blk * 96 + n] : b2[768 + blk * 96 + (n - 96)];
    }
    __syncthreads();

    f16x8 Bf1[3][6], Bf2[3][6];
    #pragma unroll
    for (int c = 0; c < 3; ++c) {
        const int nq = (n0 + c * 16) < 96;
        const int nl = n0 + c * 16 + (lane & 15) - (nq ? 0 : 96);
        #pragma unroll
        for (int kit = 0; kit < 6; ++kit) {
            const int kq = kit < 3;
            const int kl = kit * 32 + ((lane >> 4) << 3) - (kq ? 0 : 96);
            const int quad = kq ? (nq ? 0 : 1) : (nq ? 1 : 0);
            const bool flip = (!kq) && nq;
            {
                f16x8 v = *(const f16x8*)(WT + quad * 9984 + nl * 104 + kl);
                if (flip) { u32x4 u = __builtin_bit_cast(u32x4, v); u ^= 0x80008000u; v = __builtin_bit_cast(f16x8, u); }
                Bf1[c][kit] = v;
            }
            {
                f16x8 v = *(const f16x8*)(WT + (2 + quad) * 9984 + nl * 104 + kl);
                if (flip) { u32x4 u = __builtin_bit_cast(u32x4, v); u ^= 0x80008000u; v = __builtin_bit_cast(f16x8, u); }
                Bf2[c][kit] = v;
            }
        }
    }

    const unsigned short* Xl = Xs + (lane & 15) * 200 + ((lane >> 4) << 3);
    const int rowoff = ((lane >> 4) << 2);

    for (int t = 0; t < K3_TILES; ++t) {
        const int pos0 = (blockIdx.x * K3_TILES + t) * 128;
        // 16-byte moves: 3072 iters x 8 shorts = full 128x192 augmented tile
        for (int idx = tid; idx < 3072; idx += BDIM) {
            int plane = idx / 1536, rem = idx % 1536;
            int row = rem / 12, ch = (rem % 12) * 8;
            const unsigned short* src = plane ? Ri : Rr;
            u32x4 v = *(const u32x4*)(src + (size_t)(pos0 + row) * 768 + blk * 96 + ch);
            *(u32x4*)(Xs + row * 200 + plane * 96 + ch) = v;
        }
        __syncthreads();

        f32x4 acc[8][3];
        #pragma unroll
        for (int r = 0; r < 8; ++r)
            #pragma unroll
            for (int c = 0; c < 3; ++c)
                acc[r][c] = (f32x4){bias1[c], bias1[c], bias1[c], bias1[c]};
        #pragma unroll
        for (int kit = 0; kit < 6; ++kit) {
            f16x8 A[8];
            #pragma unroll
            for (int r = 0; r < 8; ++r)
                A[r] = *(const f16x8*)(Xl + r * 3200 + kit * 32);
            #pragma unroll
            for (int r = 0; r < 8; ++r)
                #pragma unroll
                for (int c = 0; c < 3; ++c)
                    acc[r][c] = __builtin_amdgcn_mfma_f32_16x16x32_f16(A[r], Bf1[c][kit], acc[r][c], 0, 0, 0);
        }
        __syncthreads();
        #pragma unroll
        for (int r = 0; r < 8; ++r)
            #pragma unroll
            for (int c = 0; c < 3; ++c) {
                int ncol = n0 + c * 16 + (lane & 15);
                #pragma unroll
                for (int reg = 0; reg < 4; ++reg) {
                    int row = r * 16 + rowoff + reg;
                    Xs[row * 200 + ncol] = f2h(fmaxf(acc[r][c][reg], 0.f));
                }
            }
        __syncthreads();

        #pragma unroll
        for (int r = 0; r < 8; ++r)
            #pragma unroll
            for (int c = 0; c < 3; ++c)
                acc[r][c] = (f32x4){bias2[c], bias2[c], bias2[c], bias2[c]};
        #pragma unroll
        for (int kit = 0; kit < 6; ++kit) {
            f16x8 A[8];
            #pragma unroll
            for (int r = 0; r < 8; ++r)
                A[r] = *(const f16x8*)(Xl + r * 3200 + kit * 32);
            #pragma unroll
            for (int r = 0; r < 8; ++r)
                #pragma unroll
                for (int c = 0; c < 3; ++c)
                    acc[r][c] = __builtin_amdgcn_mfma_f32_16x16x32_f16(A[r], Bf2[c][kit], acc[r][c], 0, 0, 0);
        }
        #pragma unroll
        for (int r = 0; r < 8; ++r)
            #pragma unroll
            for (int c = 0; c < 3; ++c) {
                int ncol = n0 + c * 16 + (lane & 15);
                unsigned short* dst = (ncol < 96) ? Rr : Ri;
                int nch = (ncol < 96) ? ncol : ncol - 96;
                #pragma unroll
                for (int reg = 0; reg < 4; ++reg) {
                    int row = r * 16 + rowoff + reg;
                    float v = acc[r][c][reg];
                    v = (v > 0.01f) ? v - 0.01f : ((v < -0.01f) ? v + 0.01f : 0.f);
                    dst[(size_t)(pos0 + row) * 768 + blk * 96 + nch] = f2h(v);
                }
            }
        __syncthreads();
    }
}

// ---------------- K5m: c2r inverse over W via f16 MFMA + residual -----------
// out[w][c] = sum_{wm=0}^{64} Cw[w][wm] Xr[wm][c] + Sn[w][wm] Xi[wm][c] + x[w][c]
// Cw = a*cos(2pi w wm/128)/128, Sn = -a*sin(...)/128, a = 1 (DC/Nyq) else 2.
// Twiddles (A operand) computed per-lane into REGISTERS (48 sincos in prologue).
// grid (B*H = 512), block 256 (4 waves M-split). K = 65 padded to 96.
// LDS: Xt[2][64][104] f16 = 26,624 B (c-local x wm, rows 65..95 zeroed).
constexpr int K5PAD = 104;
__global__ __launch_bounds__(BDIM, 1) void k5m(const unsigned short* __restrict__ Rr,
                                               const unsigned short* __restrict__ Ri,
                                               const float* __restrict__ x,
                                               float* __restrict__ out) {
    __shared__ unsigned short Xt[2][64][K5PAD];
    const int tid = threadIdx.x;
    const int lane = tid & 63;
    const int wv = tid >> 6;
    const int b = blockIdx.x >> 7, h = blockIdx.x & 127;
    const size_t rowbase = ((size_t)(b * WM) * 128 + h) * 768;   // + wm*98304 + c
    const size_t obase = ((size_t)(b * 16384 + h * 128)) * 768;  // + w*768 + c

    // ---- per-lane twiddle A-fragments (registers only)
    // A[row=wv*32+rf*16+(lane&15)][k=ks*32+(lane>>4)*8+j]
    f16x8 Ca[2][3], Sa[2][3];
    {
        const int wrow_lo = wv * 32 + (lane & 15);
        #pragma unroll
        for (int rf = 0; rf < 2; ++rf) {
            const int wrow = wrow_lo + rf * 16;
            #pragma unroll
            for (int ks = 0; ks < 3; ++ks) {
                f16x8 cv, sv;
                #pragma unroll
                for (int j = 0; j < 8; ++j) {
                    int wm = ks * 32 + ((lane >> 4) << 3) + j;
                    float alpha = (wm > 64) ? 0.f : ((wm == 0 || wm == 64) ? 1.f : 2.f);
                    float th = (float)((wrow * wm) & 127) * 0.04908738521234052f;
                    float s, c; __sincosf(th, &s, &c);
                    cv[j] = (_Float16)(alpha * 0.0078125f * c);
                    sv[j] = (_Float16)(-alpha * 0.0078125f * s);
                }
                Ca[rf][ks] = cv;
                Sa[rf][ks] = sv;
            }
        }
    }

    // ---- zero K-pad rows (wm 65..95) once; never rewritten
    for (int idx = tid; idx < 2 * 64 * 31; idx += BDIM) {
        int plane = idx / (64 * 31), rem = idx % (64 * 31);
        int cl = rem / 31, wm = 65 + rem % 31;
        Xt[plane][cl][wm] = 0;
    }

    // ---- prefetch tile 0 (wm lane-major: conflict-free LDS scatter)
    // iter i: plane = i>>1, grp = (i&1)*4 + wv, wm = lane
    unsigned short pfs[4][8], pfn[8];
    #pragma unroll
    for (int i = 0; i < 4; ++i) {
        const unsigned short* src = (i >> 1) ? Ri : Rr;
        int grp = (i & 1) * 4 + wv;
        *(u32x4*)&pfs[i][0] = *(const u32x4*)(src + rowbase + (size_t)lane * 98304 + grp * 8);
    }
    if (tid < 16) {   // Nyquist row wm=64: plane = tid>>3, grp = tid&7
        const unsigned short* src = (tid >> 3) ? Ri : Rr;
        *(u32x4*)&pfn[0] = *(const u32x4*)(src + rowbase + (size_t)64 * 98304 + (tid & 7) * 8);
    }

    for (int t = 0; t < 12; ++t) {
        // ---- scatter staged regs into LDS [c_local][wm]
        #pragma unroll
        for (int i = 0; i < 4; ++i) {
            int plane = i >> 1, grp = (i & 1) * 4 + wv;
            #pragma unroll
            for (int j = 0; j < 8; ++j)
                Xt[plane][grp * 8 + j][lane] = pfs[i][j];
        }
        if (tid < 16) {
            int plane = tid >> 3, grp = tid & 7;
            #pragma unroll
            for (int j = 0; j < 8; ++j)
                Xt[plane][grp * 8 + j][64] = pfn[j];
        }
        // ---- issue next tile's loads (in flight during MFMA)
        if (t < 11) {
            #pragma unroll
            for (int i = 0; i < 4; ++i) {
                const unsigned short* src = (i >> 1) ? Ri : Rr;
                int grp = (i & 1) * 4 + wv;
                *(u32x4*)&pfs[i][0] = *(const u32x4*)(src + rowbase + (size_t)lane * 98304 + (t + 1) * 64 + grp * 8);
            }
            if (tid < 16) {
                const unsigned short* src = (tid >> 3) ? Ri : Rr;
                *(u32x4*)&pfn[0] = *(const u32x4*)(src + rowbase + (size_t)64 * 98304 + (t + 1) * 64 + (tid & 7) * 8);
            }
        }
        __syncthreads();

        // ---- MFMA: acc[rf][cf] (real output only)
        f32x4 acc[2][4];
        #pragma unroll
        for (int rf = 0; rf < 2; ++rf)
            #pragma unroll
            for (int cf = 0; cf < 4; ++cf)
                acc[rf][cf] = (f32x4){0, 0, 0, 0};
        const int koff = (lane >> 4) << 3;
        #pragma unroll
        for (int ks = 0; ks < 3; ++ks) {
            #pragma unroll
            for (int cf = 0; cf < 4; ++cf) {
                const int cl = cf * 16 + (lane & 15);
                f16x8 Br = *(const f16x8*)(&Xt[0][cl][ks * 32 + koff]);
                f16x8 Bi = *(const f16x8*)(&Xt[1][cl][ks * 32 + koff]);
                #pragma unroll
                for (int rf = 0; rf < 2; ++rf) {
                    acc[rf][cf] = __builtin_amdgcn_mfma_f32_16x16x32_f16(Ca[rf][ks], Br, acc[rf][cf], 0, 0, 0);
                    acc[rf][cf] = __builtin_amdgcn_mfma_f32_16x16x32_f16(Sa[rf][ks], Bi, acc[rf][cf], 0, 0, 0);
                }
            }
        }
        // ---- epilogue: + x residual, fp32 store
        #pragma unroll
        for (int rf = 0; rf < 2; ++rf)
            #pragma unroll
            for (int cf = 0; cf < 4; ++cf) {
                int col = t * 64 + cf * 16 + (lane & 15);
                int row0 = wv * 32 + rf * 16 + ((lane >> 4) << 2);
                #pragma unroll
                for (int reg = 0; reg < 4; ++reg) {
                    size_t a = obase + (size_t)(row0 + reg) * 768 + col;
                    out[a] = acc[rf][cf][reg] + x[a];
                }
            }
        __syncthreads();   // LDS safe to overwrite next tile
    }
}

extern "C" void kernel_launch(void* const* d_in, const int* in_sizes, int n_in,
                              void* d_out, int out_size, void* d_ws, size_t ws_size,
                              hipStream_t stream) {
    const float* x  = (const float*)d_in[0];
    const float* w1 = (const float*)d_in[1];
    const float* b1 = (const float*)d_in[2];
    const float* w2 = (const float*)d_in[3];
    const float* b2 = (const float*)d_in[4];
    float* out = (float*)d_out;

    unsigned short* Rr = (unsigned short*)d_ws;
    unsigned short* Ri = Rr + NSPEC;

    const size_t k2lds = (size_t)(2 * 128 * TSTR + 2 * 64 * TSTR) * 2;  // 104,448 B

    k1_rfft_w<<<dim3(512, 12), BDIM, 0, stream>>>(x, Rr, Ri);
    k2m<0><<<dim3(260, 2), BDIM, k2lds, stream>>>(Rr, Ri);
    k3_mlp<<<dim3(130, 8), BDIM, 131072, stream>>>(Rr, Ri, w1, b1, w2, b2);
    k2m<1><<<dim3(260, 2), BDIM, k2lds, stream>>>(Rr, Ri);
    k5m<<<dim3(512), BDIM, 0, stream>>>(Rr, Ri, x, out);
}

// Round 6
// 505.404 us; speedup vs baseline: 7.7583x; 1.3186x over previous
//
#include <hip/hip_runtime.h>
#include <hip/hip_bf16.h>

#define BDIM 256
constexpr int Bc = 4, Hc = 128, Wcn = 128, Cc = 768, WM = 65, NB = 8, BS = 96;
constexpr int NROWS = Bc * WM * Hc;              // 33280 spectral rows (b, wm, h)
constexpr size_t NSPEC = (size_t)NROWS * Cc;     // 25,559,040 elems per r/i plane

typedef __attribute__((ext_vector_type(8))) _Float16 f16x8;
typedef __attribute__((ext_vector_type(4))) float f32x4;
typedef __attribute__((ext_vector_type(4))) unsigned int u32x4;

__device__ __forceinline__ unsigned short f2h(float f) {
    return __builtin_bit_cast(unsigned short, (_Float16)f);
}
__device__ __forceinline__ float h2f(unsigned short s) {
    return (float)__builtin_bit_cast(_Float16, s);
}

// ---------------- K1m: rfft over W via f16 MFMA (scale 1/128) ---------------
// Row-folded square GEMM: M=128 rows = {Yr[0..64], Yi[1..63]}, K=128, N=768.
// A (twiddles) in registers: r<65: cos(2pi r w/128)/128 ; r>=65: -sin(2pi (r-64) w/128)/128
// grid (B*H = 512), block 256 (4 waves M-split, 32 rows each).
// LDS: Xt[64][136] f16 (c_local x w, w lane-major scatter) = 17,408 B.
constexpr int K1PAD = 136;
__global__ __launch_bounds__(BDIM, 1) void k1m(const float* __restrict__ x,
                                               unsigned short* __restrict__ Rr,
                                               unsigned short* __restrict__ Ri) {
    __shared__ unsigned short Xt[64][K1PAD];
    const int tid = threadIdx.x;
    const int lane = tid & 63;
    const int wv = tid >> 6;
    const int b = blockIdx.x >> 7, h = blockIdx.x & 127;
    const float* xp = x + ((size_t)(b * 16384 + h * 128)) * 768;   // + w*768 + c
    const size_t sbase = ((size_t)(b * WM) * 128 + h) * 768;       // + wm*98304 + c

    // ---- per-lane twiddle A-fragments (registers only)
    f16x8 Af[2][4];
    {
        const int rlo = wv * 32 + (lane & 15);
        #pragma unroll
        for (int rf = 0; rf < 2; ++rf) {
            const int r = rlo + rf * 16;
            const int m = (r < 65) ? r : (r - 64);
            #pragma unroll
            for (int ks = 0; ks < 4; ++ks) {
                f16x8 v;
                #pragma unroll
                for (int j = 0; j < 8; ++j) {
                    int k = ks * 32 + ((lane >> 4) << 3) + j;
                    float th = (float)((m * k) & 127) * 0.04908738521234052f;
                    float s, c; __sincosf(th, &s, &c);
                    v[j] = (_Float16)(((r < 65) ? c : -s) * 0.0078125f);
                }
                Af[rf][ks] = v;
            }
        }
    }

    // ---- prefetch tile 0: w = tid&127, cg = tid>>7; 8 float4 = 32 c's
    const int w = tid & 127, cg = tid >> 7;
    float4 pfv[8];
    #pragma unroll
    for (int q = 0; q < 8; ++q)
        pfv[q] = *(const float4*)(xp + (size_t)w * 768 + cg * 32 + q * 4);

    const int koff = (lane >> 4) << 3;

    for (int t = 0; t < 12; ++t) {
        // ---- scatter staged regs into LDS [c_local][w] (w lane-major: 2-way free)
        #pragma unroll
        for (int q = 0; q < 8; ++q) {
            float4 v = pfv[q];
            int cb = cg * 32 + q * 4;
            Xt[cb + 0][w] = f2h(v.x);
            Xt[cb + 1][w] = f2h(v.y);
            Xt[cb + 2][w] = f2h(v.z);
            Xt[cb + 3][w] = f2h(v.w);
        }
        // ---- issue next tile's loads (in flight during MFMA)
        if (t < 11) {
            #pragma unroll
            for (int q = 0; q < 8; ++q)
                pfv[q] = *(const float4*)(xp + (size_t)w * 768 + (t + 1) * 64 + cg * 32 + q * 4);
        }
        __syncthreads();

        // ---- MFMA: acc[rf][cf]
        f32x4 acc[2][4];
        #pragma unroll
        for (int rf = 0; rf < 2; ++rf)
            #pragma unroll
            for (int cf = 0; cf < 4; ++cf)
                acc[rf][cf] = (f32x4){0, 0, 0, 0};
        #pragma unroll
        for (int ks = 0; ks < 4; ++ks) {
            #pragma unroll
            for (int cf = 0; cf < 4; ++cf) {
                const int cl = cf * 16 + (lane & 15);
                f16x8 Bf = *(const f16x8*)(&Xt[cl][ks * 32 + koff]);
                #pragma unroll
                for (int rf = 0; rf < 2; ++rf)
                    acc[rf][cf] = __builtin_amdgcn_mfma_f32_16x16x32_f16(Af[rf][ks], Bf, acc[rf][cf], 0, 0, 0);
            }
        }
        // ---- store: rows <65 -> Rr[wm=r], rows >=65 -> Ri[wm=r-64]
        #pragma unroll
        for (int rf = 0; rf < 2; ++rf)
            #pragma unroll
            for (int cf = 0; cf < 4; ++cf) {
                int col = t * 64 + cf * 16 + (lane & 15);
                int r0 = wv * 32 + rf * 16 + ((lane >> 4) << 2);
                #pragma unroll
                for (int reg = 0; reg < 4; ++reg) {
                    int r = r0 + reg;
                    if (r < 65) {
                        Rr[sbase + (size_t)r * 98304 + col] = f2h(acc[rf][cf][reg]);
                        if (r == 0)  Ri[sbase + col] = 0;                       // Ri[DC] = 0
                        if (r == 64) Ri[sbase + (size_t)64 * 98304 + col] = 0;  // Ri[Nyq] = 0
                    } else {
                        Ri[sbase + (size_t)(r - 64) * 98304 + col] = f2h(acc[rf][cf][reg]);
                    }
                }
            }
        __syncthreads();   // LDS safe to overwrite next tile
    }
}

// ---------------- K2m: complex DFT over H via f16 MFMA ----------------------
// Y[h2][c] = sum_h F[h2][h] X[h][c];  fwd: Yr=C.Xr+S.Xi, Yi=C.Xi-S.Xr
//                                     inv: Yr=C.Xr-S.Xi, Yi=C.Xi+S.Xr
// grid (260 slabs, 2 c-halves), block 256 (4 waves M-split, 32 rows each).
// LDS: C[128][136], S[128][136], Xt_r[64][136], Xt_i[64][136] = 104,448 B
constexpr int TSTR = 136;
template <int INV>
__global__ __launch_bounds__(BDIM, 1) void k2m(unsigned short* __restrict__ Rr,
                                               unsigned short* __restrict__ Ri) {
    extern __shared__ unsigned short lds[];
    unsigned short* Ct = lds;                  // [128][TSTR]
    unsigned short* St = Ct + 128 * TSTR;
    unsigned short* Xtr = St + 128 * TSTR;     // [64][TSTR]
    unsigned short* Xti = Xtr + 64 * TSTR;

    const int tid = threadIdx.x;
    const int lane = tid & 63;
    const int wv = tid >> 6;
    const size_t rowbase = (size_t)blockIdx.x * 128 * 768;
    const int chalf = blockIdx.y * 384;

    // build twiddle tables (p = h2*h mod 128)
    for (int idx = tid; idx < 16384; idx += BDIM) {
        int h2 = idx >> 7, h = idx & 127;
        float th = (float)((h2 * h) & 127) * 0.04908738521234052f;  // 2pi/128
        float s, c; __sincosf(th, &s, &c);
        Ct[h2 * TSTR + h] = f2h(c);
        St[h2 * TSTR + h] = f2h(s);
    }

    const int hme = tid & 127, cgme = tid >> 7;   // staging: h = lane-major
    unsigned short pfs[8][8];
    #pragma unroll
    for (int p = 0; p < 8; ++p) {
        const unsigned short* src = (p >> 2) ? Ri : Rr;
        int c0 = chalf + ((p & 3) * 2 + cgme) * 8;
        *(u32x4*)&pfs[p][0] = *(const u32x4*)(src + rowbase + (size_t)hme * 768 + c0);
    }
    __syncthreads();   // twiddle tables ready

    const int arow0 = wv * 32 + (lane & 15);
    const int koff = (lane >> 4) * 8;

    for (int t = 0; t < 6; ++t) {
        // ---- scatter-transpose staged regs into LDS (h lane-major: conflict-free)
        #pragma unroll
        for (int p = 0; p < 8; ++p) {
            unsigned short* dst = (p >> 2) ? Xti : Xtr;
            int cl = ((p & 3) * 2 + cgme) * 8;
            #pragma unroll
            for (int j = 0; j < 8; ++j)
                dst[(cl + j) * TSTR + hme] = pfs[p][j];
        }
        // ---- issue next tile's global loads (in flight during compute)
        if (t < 5) {
            #pragma unroll
            for (int p = 0; p < 8; ++p) {
                const unsigned short* src = (p >> 2) ? Ri : Rr;
                int c0 = chalf + (t + 1) * 64 + ((p & 3) * 2 + cgme) * 8;
                *(u32x4*)&pfs[p][0] = *(const u32x4*)(src + rowbase + (size_t)hme * 768 + c0);
            }
        }
        __syncthreads();

        // ---- MFMA: acc[rf][cf], rf in {0,1} (row frags), cf in {0..3} (col frags)
        f32x4 accr[2][4], acci[2][4];
        #pragma unroll
        for (int rf = 0; rf < 2; ++rf)
            #pragma unroll
            for (int cf = 0; cf < 4; ++cf) {
                accr[rf][cf] = (f32x4){0, 0, 0, 0};
                acci[rf][cf] = (f32x4){0, 0, 0, 0};
            }
        #pragma unroll
        for (int ks = 0; ks < 4; ++ks) {
            f16x8 Cf[2], Sp[2], Sn[2];
            #pragma unroll
            for (int rf = 0; rf < 2; ++rf) {
                int off = (arow0 + rf * 16) * TSTR + ks * 32 + koff;
                Cf[rf] = *(const f16x8*)(Ct + off);
                f16x8 s = *(const f16x8*)(St + off);
                u32x4 u = __builtin_bit_cast(u32x4, s);
                u ^= 0x80008000u;
                Sp[rf] = s;
                Sn[rf] = __builtin_bit_cast(f16x8, u);
            }
            #pragma unroll
            for (int cf = 0; cf < 4; ++cf) {
                int boff = (cf * 16 + (lane & 15)) * TSTR + ks * 32 + koff;
                f16x8 Br = *(const f16x8*)(Xtr + boff);
                f16x8 Bi = *(const f16x8*)(Xti + boff);
                #pragma unroll
                for (int rf = 0; rf < 2; ++rf) {
                    accr[rf][cf] = __builtin_amdgcn_mfma_f32_16x16x32_f16(Cf[rf], Br, accr[rf][cf], 0, 0, 0);
                    accr[rf][cf] = __builtin_amdgcn_mfma_f32_16x16x32_f16(INV ? Sn[rf] : Sp[rf], Bi, accr[rf][cf], 0, 0, 0);
                    acci[rf][cf] = __builtin_amdgcn_mfma_f32_16x16x32_f16(Cf[rf], Bi, acci[rf][cf], 0, 0, 0);
                    acci[rf][cf] = __builtin_amdgcn_mfma_f32_16x16x32_f16(INV ? Sp[rf] : Sn[rf], Br, acci[rf][cf], 0, 0, 0);
                }
            }
        }
        // ---- store Y tile to global (f16 scalar scatter, 32B runs per 16 lanes)
        const int cbase = chalf + t * 64;
        #pragma unroll
        for (int rf = 0; rf < 2; ++rf)
            #pragma unroll
            for (int cf = 0; cf < 4; ++cf) {
                int c = cbase + cf * 16 + (lane & 15);
                int h2b = wv * 32 + rf * 16 + ((lane >> 4) << 2);
                #pragma unroll
                for (int reg = 0; reg < 4; ++reg) {
                    size_t a = rowbase + (size_t)(h2b + reg) * 768 + c;
                    Rr[a] = f2h(accr[rf][cf][reg]);
                    Ri[a] = f2h(acci[rf][cf][reg]);
                }
            }
        __syncthreads();   // LDS safe to overwrite next iteration
    }
}

// ---------------- K3: complex MLP via f16 MFMA ------------------------------
constexpr int K3_TILES = 2;
__global__ __launch_bounds__(BDIM, 1) void k3_mlp(unsigned short* __restrict__ Rr,
                                                  unsigned short* __restrict__ Ri,
                                                  const float* __restrict__ w1,
                                                  const float* __restrict__ b1,
                                                  const float* __restrict__ w2,
                                                  const float* __restrict__ b2) {
    extern __shared__ char smem[];
    unsigned short* WT = (unsigned short*)smem;        // [mat][96][104]
    unsigned short* Xs = WT + 4 * 96 * 104;            // [128][200] augmented

    const int tid = threadIdx.x;
    const int lane = tid & 63;
    const int w = tid >> 6;
    const int n0 = w * 48;
    const int blk = blockIdx.y;

    {
        const float* src0 = w1 + (size_t)blk * 9216;
        const float* src1 = w1 + (size_t)(8 + blk) * 9216;
        const float* src2 = w2 + (size_t)blk * 9216;
        const float* src3 = w2 + (size_t)(8 + blk) * 9216;
        for (int idx = tid; idx < 9216; idx += BDIM) {
            int k = idx / 96, n = idx % 96;
            int d = n * 104 + k;
            WT[d]             = f2h(src0[idx]);
            WT[9984 + d]      = f2h(src1[idx]);
            WT[2 * 9984 + d]  = f2h(src2[idx]);
            WT[3 * 9984 + d]  = f2h(src3[idx]);
        }
    }
    float bias1[3], bias2[3];
    #pragma unroll
    for (int c = 0; c < 3; ++c) {
        int n = n0 + c * 16 + (lane & 15);
        bias1[c] = (n < 96) ? b1[blk * 96 + n] : b1[768 + blk * 96 + (n - 96)];
        bias2[c] = (n < 96) ? b2[blk * 96 + n] : b2[768 + blk * 96 + (n - 96)];
    }
    __syncthreads();

    f16x8 Bf1[3][6], Bf2[3][6];
    #pragma unroll
    for (int c = 0; c < 3; ++c) {
        const int nq = (n0 + c * 16) < 96;
        const int nl = n0 + c * 16 + (lane & 15) - (nq ? 0 : 96);
        #pragma unroll
        for (int kit = 0; kit < 6; ++kit) {
            const int kq = kit < 3;
            const int kl = kit * 32 + ((lane >> 4) << 3) - (kq ? 0 : 96);
            const int quad = kq ? (nq ? 0 : 1) : (nq ? 1 : 0);
            const bool flip = (!kq) && nq;
            {
                f16x8 v = *(const f16x8*)(WT + quad * 9984 + nl * 104 + kl);
                if (flip) { u32x4 u = __builtin_bit_cast(u32x4, v); u ^= 0x80008000u; v = __builtin_bit_cast(f16x8, u); }
                Bf1[c][kit] = v;
            }
            {
                f16x8 v = *(const f16x8*)(WT + (2 + quad) * 9984 + nl * 104 + kl);
                if (flip) { u32x4 u = __builtin_bit_cast(u32x4, v); u ^= 0x80008000u; v = __builtin_bit_cast(f16x8, u); }
                Bf2[c][kit] = v;
            }
        }
    }

    const unsigned short* Xl = Xs + (lane & 15) * 200 + ((lane >> 4) << 3);
    const int rowoff = ((lane >> 4) << 2);

    for (int t = 0; t < K3_TILES; ++t) {
        const int pos0 = (blockIdx.x * K3_TILES + t) * 128;
        // 16-byte moves: 3072 iters x 8 shorts = full 128x192 augmented tile
        for (int idx = tid; idx < 3072; idx += BDIM) {
            int plane = idx / 1536, rem = idx % 1536;
            int row = rem / 12, ch = (rem % 12) * 8;
            const unsigned short* src = plane ? Ri : Rr;
            u32x4 v = *(const u32x4*)(src + (size_t)(pos0 + row) * 768 + blk * 96 + ch);
            *(u32x4*)(Xs + row * 200 + plane * 96 + ch) = v;
        }
        __syncthreads();

        f32x4 acc[8][3];
        #pragma unroll
        for (int r = 0; r < 8; ++r)
            #pragma unroll
            for (int c = 0; c < 3; ++c)
                acc[r][c] = (f32x4){bias1[c], bias1[c], bias1[c], bias1[c]};
        #pragma unroll
        for (int kit = 0; kit < 6; ++kit) {
            f16x8 A[8];
            #pragma unroll
            for (int r = 0; r < 8; ++r)
                A[r] = *(const f16x8*)(Xl + r * 3200 + kit * 32);
            #pragma unroll
            for (int r = 0; r < 8; ++r)
                #pragma unroll
                for (int c = 0; c < 3; ++c)
                    acc[r][c] = __builtin_amdgcn_mfma_f32_16x16x32_f16(A[r], Bf1[c][kit], acc[r][c], 0, 0, 0);
        }
        __syncthreads();
        #pragma unroll
        for (int r = 0; r < 8; ++r)
            #pragma unroll
            for (int c = 0; c < 3; ++c) {
                int ncol = n0 + c * 16 + (lane & 15);
                #pragma unroll
                for (int reg = 0; reg < 4; ++reg) {
                    int row = r * 16 + rowoff + reg;
                    Xs[row * 200 + ncol] = f2h(fmaxf(acc[r][c][reg], 0.f));
                }
            }
        __syncthreads();

        #pragma unroll
        for (int r = 0; r < 8; ++r)
            #pragma unroll
            for (int c = 0; c < 3; ++c)
                acc[r][c] = (f32x4){bias2[c], bias2[c], bias2[c], bias2[c]};
        #pragma unroll
        for (int kit = 0; kit < 6; ++kit) {
            f16x8 A[8];
            #pragma unroll
            for (int r = 0; r < 8; ++r)
                A[r] = *(const f16x8*)(Xl + r * 3200 + kit * 32);
            #pragma unroll
            for (int r = 0; r < 8; ++r)
                #pragma unroll
                for (int c = 0; c < 3; ++c)
                    acc[r][c] = __builtin_amdgcn_mfma_f32_16x16x32_f16(A[r], Bf2[c][kit], acc[r][c], 0, 0, 0);
        }
        #pragma unroll
        for (int r = 0; r < 8; ++r)
            #pragma unroll
            for (int c = 0; c < 3; ++c) {
                int ncol = n0 + c * 16 + (lane & 15);
                unsigned short* dst = (ncol < 96) ? Rr : Ri;
                int nch = (ncol < 96) ? ncol : ncol - 96;
                #pragma unroll
                for (int reg = 0; reg < 4; ++reg) {
                    int row = r * 16 + rowoff + reg;
                    float v = acc[r][c][reg];
                    v = (v > 0.01f) ? v - 0.01f : ((v < -0.01f) ? v + 0.01f : 0.f);
                    dst[(size_t)(pos0 + row) * 768 + blk * 96 + nch] = f2h(v);
                }
            }
        __syncthreads();
    }
}

// ---------------- K5m: c2r inverse over W via f16 MFMA + residual -----------
// out[w][c] = sum_{wm=0}^{64} Cw[w][wm] Xr[wm][c] + Sn[w][wm] Xi[wm][c] + x[w][c]
// Cw = a*cos(2pi w wm/128)/128, Sn = -a*sin(...)/128, a = 1 (DC/Nyq) else 2.
// grid (B*H = 512), block 256 (4 waves M-split). K = 65 padded to 96.
// LDS: Xt[2][64][104] f16 = 26,624 B (c-local x wm, rows 65..95 zeroed).
constexpr int K5PAD = 104;
__global__ __launch_bounds__(BDIM, 1) void k5m(const unsigned short* __restrict__ Rr,
                                               const unsigned short* __restrict__ Ri,
                                               const float* __restrict__ x,
                                               float* __restrict__ out) {
    __shared__ unsigned short Xt[2][64][K5PAD];
    const int tid = threadIdx.x;
    const int lane = tid & 63;
    const int wv = tid >> 6;
    const int b = blockIdx.x >> 7, h = blockIdx.x & 127;
    const size_t rowbase = ((size_t)(b * WM) * 128 + h) * 768;   // + wm*98304 + c
    const size_t obase = ((size_t)(b * 16384 + h * 128)) * 768;  // + w*768 + c

    f16x8 Ca[2][3], Sa[2][3];
    {
        const int wrow_lo = wv * 32 + (lane & 15);
        #pragma unroll
        for (int rf = 0; rf < 2; ++rf) {
            const int wrow = wrow_lo + rf * 16;
            #pragma unroll
            for (int ks = 0; ks < 3; ++ks) {
                f16x8 cv, sv;
                #pragma unroll
                for (int j = 0; j < 8; ++j) {
                    int wm = ks * 32 + ((lane >> 4) << 3) + j;
                    float alpha = (wm > 64) ? 0.f : ((wm == 0 || wm == 64) ? 1.f : 2.f);
                    float th = (float)((wrow * wm) & 127) * 0.04908738521234052f;
                    float s, c; __sincosf(th, &s, &c);
                    cv[j] = (_Float16)(alpha * 0.0078125f * c);
                    sv[j] = (_Float16)(-alpha * 0.0078125f * s);
                }
                Ca[rf][ks] = cv;
                Sa[rf][ks] = sv;
            }
        }
    }

    for (int idx = tid; idx < 2 * 64 * 31; idx += BDIM) {
        int plane = idx / (64 * 31), rem = idx % (64 * 31);
        int cl = rem / 31, wm = 65 + rem % 31;
        Xt[plane][cl][wm] = 0;
    }

    unsigned short pfs[4][8], pfn[8];
    #pragma unroll
    for (int i = 0; i < 4; ++i) {
        const unsigned short* src = (i >> 1) ? Ri : Rr;
        int grp = (i & 1) * 4 + wv;
        *(u32x4*)&pfs[i][0] = *(const u32x4*)(src + rowbase + (size_t)lane * 98304 + grp * 8);
    }
    if (tid < 16) {
        const unsigned short* src = (tid >> 3) ? Ri : Rr;
        *(u32x4*)&pfn[0] = *(const u32x4*)(src + rowbase + (size_t)64 * 98304 + (tid & 7) * 8);
    }

    for (int t = 0; t < 12; ++t) {
        #pragma unroll
        for (int i = 0; i < 4; ++i) {
            int plane = i >> 1, grp = (i & 1) * 4 + wv;
            #pragma unroll
            for (int j = 0; j < 8; ++j)
                Xt[plane][grp * 8 + j][lane] = pfs[i][j];
        }
        if (tid < 16) {
            int plane = tid >> 3, grp = tid & 7;
            #pragma unroll
            for (int j = 0; j < 8; ++j)
                Xt[plane][grp * 8 + j][64] = pfn[j];
        }
        if (t < 11) {
            #pragma unroll
            for (int i = 0; i < 4; ++i) {
                const unsigned short* src = (i >> 1) ? Ri : Rr;
                int grp = (i & 1) * 4 + wv;
                *(u32x4*)&pfs[i][0] = *(const u32x4*)(src + rowbase + (size_t)lane * 98304 + (t + 1) * 64 + grp * 8);
            }
            if (tid < 16) {
                const unsigned short* src = (tid >> 3) ? Ri : Rr;
                *(u32x4*)&pfn[0] = *(const u32x4*)(src + rowbase + (size_t)64 * 98304 + (t + 1) * 64 + (tid & 7) * 8);
            }
        }
        __syncthreads();

        f32x4 acc[2][4];
        #pragma unroll
        for (int rf = 0; rf < 2; ++rf)
            #pragma unroll
            for (int cf = 0; cf < 4; ++cf)
                acc[rf][cf] = (f32x4){0, 0, 0, 0};
        const int koff = (lane >> 4) << 3;
        #pragma unroll
        for (int ks = 0; ks < 3; ++ks) {
            #pragma unroll
            for (int cf = 0; cf < 4; ++cf) {
                const int cl = cf * 16 + (lane & 15);
                f16x8 Br = *(const f16x8*)(&Xt[0][cl][ks * 32 + koff]);
                f16x8 Bi = *(const f16x8*)(&Xt[1][cl][ks * 32 + koff]);
                #pragma unroll
                for (int rf = 0; rf < 2; ++rf) {
                    acc[rf][cf] = __builtin_amdgcn_mfma_f32_16x16x32_f16(Ca[rf][ks], Br, acc[rf][cf], 0, 0, 0);
                    acc[rf][cf] = __builtin_amdgcn_mfma_f32_16x16x32_f16(Sa[rf][ks], Bi, acc[rf][cf], 0, 0, 0);
                }
            }
        }
        #pragma unroll
        for (int rf = 0; rf < 2; ++rf)
            #pragma unroll
            for (int cf = 0; cf < 4; ++cf) {
                int col = t * 64 + cf * 16 + (lane & 15);
                int row0 = wv * 32 + rf * 16 + ((lane >> 4) << 2);
                #pragma unroll
                for (int reg = 0; reg < 4; ++reg) {
                    size_t a = obase + (size_t)(row0 + reg) * 768 + col;
                    out[a] = acc[rf][cf][reg] + x[a];
                }
            }
        __syncthreads();
    }
}

extern "C" void kernel_launch(void* const* d_in, const int* in_sizes, int n_in,
                              void* d_out, int out_size, void* d_ws, size_t ws_size,
                              hipStream_t stream) {
    const float* x  = (const float*)d_in[0];
    const float* w1 = (const float*)d_in[1];
    const float* b1 = (const float*)d_in[2];
    const float* w2 = (const float*)d_in[3];
    const float* b2 = (const float*)d_in[4];
    float* out = (float*)d_out;

    unsigned short* Rr = (unsigned short*)d_ws;
    unsigned short* Ri = Rr + NSPEC;

    const size_t k2lds = (size_t)(2 * 128 * TSTR + 2 * 64 * TSTR) * 2;  // 104,448 B

    k1m<<<dim3(512), BDIM, 0, stream>>>(x, Rr, Ri);
    k2m<0><<<dim3(260, 2), BDIM, k2lds, stream>>>(Rr, Ri);
    k3_mlp<<<dim3(130, 8), BDIM, 131072, stream>>>(Rr, Ri, w1, b1, w2, b2);
    k2m<1><<<dim3(260, 2), BDIM, k2lds, stream>>>(Rr, Ri);
    k5m<<<dim3(512), BDIM, 0, stream>>>(Rr, Ri, x, out);
}